// Round 9
// baseline (1719.608 us; speedup 1.0000x reference)
//
#include <hip/hip_runtime.h>
#include <hip/hip_bf16.h>
#include <math.h>

#define BT 32768        // B*T tokens
#define HH 1024

typedef unsigned short u16;
typedef __attribute__((ext_vector_type(4))) unsigned short u16x4;
typedef __attribute__((ext_vector_type(8))) unsigned short u16x8;
typedef __attribute__((ext_vector_type(8))) __bf16 bf16x8;
typedef __attribute__((ext_vector_type(4))) float f32x4;

#define DEVI static __device__ __forceinline__

DEVI u16 f2bf(float f){
  unsigned u = __builtin_bit_cast(unsigned, f);
  u += 0x7FFFu + ((u >> 16) & 1u);
  return (u16)(u >> 16);
}
DEVI float bf2f(u16 h){
  unsigned u = ((unsigned)h) << 16;
  return __builtin_bit_cast(float, u);
}
DEVI void gl_lds16(const void* g, void* l){
  __builtin_amdgcn_global_load_lds((const __attribute__((address_space(1))) void*)g,
                                   (__attribute__((address_space(3))) void*)l, 16, 0, 0);
}
// T2 swizzle: 16B-granule XOR within a 64-elem (128B) row. elem units of u16. Involution.
DEVI int swz(int row, int elem){ return elem ^ ((row & 7) << 3); }

// ---------------- elementwise prep kernels ----------------
__global__ void k_cast4(const float* __restrict__ s, u16* __restrict__ d, int n4){
  int i = blockIdx.x*blockDim.x + threadIdx.x;
  int st = gridDim.x*blockDim.x;
  for (; i < n4; i += st){
    float4 v = ((const float4*)s)[i];
    u16x4 o = { f2bf(v.x), f2bf(v.y), f2bf(v.z), f2bf(v.w) };
    ((u16x4*)d)[i] = o;
  }
}

// qb = bf16(query_token + static_context)
__global__ void k_qb(const float* __restrict__ qt, const float* __restrict__ sc,
                     u16* __restrict__ d, int n4){
  int i = blockIdx.x*blockDim.x + threadIdx.x;
  int st = gridDim.x*blockDim.x;
  for (; i < n4; i += st){
    int e = i*4; int c = e & 1023;
    float4 v = *(const float4*)&sc[e];
    float4 q = *(const float4*)&qt[c];
    u16x4 o = { f2bf(v.x+q.x), f2bf(v.y+q.y), f2bf(v.z+q.z), f2bf(v.w+q.w) };
    ((u16x4*)d)[i] = o;
  }
}

__global__ void k_copyf(const float* __restrict__ s, float* __restrict__ d, int n){
  int i = blockIdx.x*blockDim.x + threadIdx.x;
  int st = gridDim.x*blockDim.x;
  for (; i < n; i += st) d[i] = s[i];
}

// weights: per (t,h) softmax over raw scores sbuf[t][h][m], mean over 16 heads
__global__ void k_wsm(const float* __restrict__ s, float* __restrict__ out, int T){
  int t = blockIdx.x*blockDim.x + threadIdx.x;
  int st = gridDim.x*blockDim.x;
  for (; t < T; t += st){
    float a0 = 0.f, a1 = 0.f, a2 = 0.f;
    #pragma unroll
    for (int h = 0; h < 16; ++h){
      const float* b = s + (size_t)t*48 + h*3;
      float s0 = b[0], s1 = b[1], s2 = b[2];
      float mx = fmaxf(s0, fmaxf(s1, s2));
      float e0 = __expf(s0-mx), e1 = __expf(s1-mx), e2 = __expf(s2-mx);
      float inv = 1.f/(e0+e1+e2);
      a0 += e0*inv; a1 += e1*inv; a2 += e2*inv;
    }
    out[(size_t)t*3+0] = a0*0.0625f;
    out[(size_t)t*3+1] = a1*0.0625f;
    out[(size_t)t*3+2] = a2*0.0625f;
  }
}

// transpose-cast: s[R][C] f32 -> d[C][R] bf16
__global__ void k_transcast(const float* __restrict__ s, u16* __restrict__ d, int R, int C){
  __shared__ float tile[32][33];
  int c0 = blockIdx.x*32, r0 = blockIdx.y*32;
  int tx = threadIdx.x & 31, ty = threadIdx.x >> 5;   // 32 x 8
  #pragma unroll
  for (int i = 0; i < 32; i += 8) tile[ty+i][tx] = s[(size_t)(r0+ty+i)*C + c0+tx];
  __syncthreads();
  #pragma unroll
  for (int i = 0; i < 32; i += 8) d[(size_t)(c0+ty+i)*R + r0+tx] = f2bf(tile[tx][ty+i]);
}

// out[row] = dot(W[row,:](bf16), x(f32)) + badd[row], rows = gridDim.x*4
__global__ void k_matvec(const u16* __restrict__ W, const float* __restrict__ x,
                         const float* __restrict__ badd, float* __restrict__ out, int K){
  int row = blockIdx.x*4 + (threadIdx.x>>6);
  int lane = threadIdx.x & 63;
  float s = 0.f;
  for (int k = lane; k < K; k += 64) s += bf2f(W[(size_t)row*K + k]) * x[k];
  #pragma unroll
  for (int m = 1; m < 64; m <<= 1) s += __shfl_xor(s, m);
  if (lane == 0) out[row] = s + badd[row];
}

// ---------------- GEMM 128x128 (R2-proven) ----------------
__global__ __launch_bounds__(256, 3)
void k_gemm(const u16* __restrict__ A, int lda,
            const u16* __restrict__ B, int ldb, int K,
            const float* __restrict__ bias,
            u16* __restrict__ C, int ldc, int col0, int act)
{
  __shared__ u16 As[128*64];
  __shared__ u16 Bs[128*64];
  const int tid = threadIdx.x, lane = tid & 63, wid = tid >> 6;
  const int wr = wid >> 1, wc = wid & 1;
  const int r15 = lane & 15, g = lane >> 4;
  const int m0 = blockIdx.x * 128, n0 = blockIdx.y * 128;
  f32x4 acc[4][4] = {};

  for (int k0 = 0; k0 < K; k0 += 64){
    #pragma unroll
    for (int it = 0; it < 4; ++it){
      int c = it*256 + tid;
      int row = c >> 3;
      int ke = swz(row, (c & 7) * 8);
      gl_lds16(A + (size_t)(m0+row)*lda + (k0+ke), As + c*8);
      gl_lds16(B + (size_t)(n0+row)*ldb + (k0+ke), Bs + c*8);
    }
    __syncthreads();
    #pragma unroll
    for (int kk = 0; kk < 64; kk += 32){
      bf16x8 av[4], bvv[4];
      #pragma unroll
      for (int i = 0; i < 4; ++i){
        int row = wr*64 + i*16 + r15;
        av[i] = *(const bf16x8*)&As[row*64 + swz(row, kk + g*8)];
      }
      #pragma unroll
      for (int j = 0; j < 4; ++j){
        int row = wc*64 + j*16 + r15;
        bvv[j] = *(const bf16x8*)&Bs[row*64 + swz(row, kk + g*8)];
      }
      #pragma unroll
      for (int i = 0; i < 4; ++i)
        #pragma unroll
        for (int j = 0; j < 4; ++j)
          acc[i][j] = __builtin_amdgcn_mfma_f32_16x16x32_bf16(av[i], bvv[j], acc[i][j], 0, 0, 0);
    }
    __syncthreads();
  }
  #pragma unroll
  for (int j = 0; j < 4; ++j){
    int col = wc*64 + j*16 + r15;
    float bb = bias ? bias[n0 + col] : 0.f;
    #pragma unroll
    for (int i = 0; i < 4; ++i){
      #pragma unroll
      for (int jj = 0; jj < 4; ++jj){
        int row = wr*64 + i*16 + g*4 + jj;
        float v = acc[i][j][jj] + bb;
        if (act == 1) v = 0.5f * v * (1.f + erff(v * 0.70710678118654752f));
        C[(size_t)(m0+row)*ldc + col0 + n0 + col] = f2bf(v);
      }
    }
  }
}

// ---------------- 256x256 GEMM, 8-phase template-exact (two barriers/phase) ----------
// Phase: {12 ds_read issue || 1 half-tile gl_lds stage} -> s_barrier -> waitcnt
// [lgkmcnt(0); +vmcnt(6) at ph0,ph3] -> setprio(1) 16 MFMA setprio(0) -> s_barrier.
// Staging: ph0:A1(t+1)->opp, ph1:B1(t+1)->opp, ph2:B0(t+2)->cur, ph3:A0(t+2)->cur.
// Certification: ph3(t-1) vmcnt(6) certifies A0/A1/B0(t); ph0(t) vmcnt(6) certifies B1(t)
// -- every region certified strictly before the phase that ds_reads it. Prologue:
// 12 loads, vmcnt(4), barrier.
__global__ __launch_bounds__(512, 2)
void k_gemm8x(const u16* __restrict__ A, int lda,
              const u16* __restrict__ B, int ldb, int K,
              const float* __restrict__ bias,
              u16* __restrict__ C, int ldc, int act, int nn)
{
  __shared__ u16 As[2][2][128*64];
  __shared__ u16 Bs[2][2][128*64];
  const int tid = threadIdx.x, lane = tid & 63, wid = tid >> 6;
  const int wr = wid >> 2, wc = wid & 3;
  const int r15 = lane & 15, g = lane >> 4;
  const int cpx = gridDim.x >> 3;
  const int sid = ((int)blockIdx.x & 7) * cpx + ((int)blockIdx.x >> 3);
  const int m0 = (sid / nn) * 256, n0 = (sid % nn) * 256;
  const int nt = K >> 6;
  f32x4 acc[8][4] = {};
  const int srow = tid >> 3, scol = (tid & 7) * 8;

  auto stA = [&](int buf, int half, int t){
    int k0 = (t < nt ? t : nt-1) << 6;
    #pragma unroll
    for (int l = 0; l < 2; ++l){
      int lr = l*64 + srow;
      gl_lds16(A + (size_t)(m0 + half*128 + lr)*lda + k0 + swz(lr, scol),
               &As[buf][half][lr*64 + scol]);
    }
  };
  auto stB = [&](int buf, int half, int t){
    int k0 = (t < nt ? t : nt-1) << 6;
    #pragma unroll
    for (int l = 0; l < 2; ++l){
      int lr = l*64 + srow;
      gl_lds16(B + (size_t)(n0 + half*128 + lr)*ldb + k0 + swz(lr, scol),
               &Bs[buf][half][lr*64 + scol]);
    }
  };

  bf16x8 av[4][2], bv[2][2];
  auto loadq = [&](int buf, int MI, int NJ){
    #pragma unroll
    for (int i = 0; i < 4; ++i){
      int r = wr*64 + i*16 + r15;
      #pragma unroll
      for (int k2 = 0; k2 < 2; ++k2)
        av[i][k2] = *(const bf16x8*)&As[buf][MI][r*64 + swz(r, k2*32 + g*8)];
    }
    #pragma unroll
    for (int j = 0; j < 2; ++j){
      int cr = wc*32 + j*16 + r15;
      #pragma unroll
      for (int k2 = 0; k2 < 2; ++k2)
        bv[j][k2] = *(const bf16x8*)&Bs[buf][NJ][cr*64 + swz(cr, k2*32 + g*8)];
    }
  };
  auto mmaq = [&](int MI, int NJ){
    __builtin_amdgcn_s_setprio(1);
    #pragma unroll
    for (int k2 = 0; k2 < 2; ++k2)
      #pragma unroll
      for (int i = 0; i < 4; ++i)
        #pragma unroll
        for (int j = 0; j < 2; ++j)
          acc[MI*4+i][NJ*2+j] = __builtin_amdgcn_mfma_f32_16x16x32_bf16(
              av[i][k2], bv[j][k2], acc[MI*4+i][NJ*2+j], 0, 0, 0);
    __builtin_amdgcn_s_setprio(0);
  };

  // prologue: tile0 (A0,A1,B0,B1) + B0(1),A0(1) = 12 loads; certify tile0, keep 4 in flight
  stA(0,0,0); stA(0,1,0); stB(0,0,0); stB(0,1,0); stB(1,0,1); stA(1,0,1);
  asm volatile("s_waitcnt vmcnt(4)" ::: "memory");
  __builtin_amdgcn_s_barrier();
  __builtin_amdgcn_sched_barrier(0);

  for (int t = 0; t < nt; ++t){
    const int cur = t & 1, opp = cur ^ 1;
    // ph0: quad(A0,B0); stage A1(t+1)->opp
    loadq(cur, 0, 0);
    stA(opp, 1, t+1);
    __builtin_amdgcn_sched_barrier(0);
    __builtin_amdgcn_s_barrier();
    asm volatile("s_waitcnt vmcnt(6) lgkmcnt(0)" ::: "memory");
    __builtin_amdgcn_sched_barrier(0);
    mmaq(0, 0);
    __builtin_amdgcn_s_barrier();
    __builtin_amdgcn_sched_barrier(0);
    // ph1: quad(A1,B0); stage B1(t+1)->opp
    loadq(cur, 1, 0);
    stB(opp, 1, t+1);
    __builtin_amdgcn_sched_barrier(0);
    __builtin_amdgcn_s_barrier();
    asm volatile("s_waitcnt lgkmcnt(0)" ::: "memory");
    __builtin_amdgcn_sched_barrier(0);
    mmaq(1, 0);
    __builtin_amdgcn_s_barrier();
    __builtin_amdgcn_sched_barrier(0);
    // ph2: quad(A0,B1); stage B0(t+2)->cur
    loadq(cur, 0, 1);
    stB(cur, 0, t+2);
    __builtin_amdgcn_sched_barrier(0);
    __builtin_amdgcn_s_barrier();
    asm volatile("s_waitcnt lgkmcnt(0)" ::: "memory");
    __builtin_amdgcn_sched_barrier(0);
    mmaq(0, 1);
    __builtin_amdgcn_s_barrier();
    __builtin_amdgcn_sched_barrier(0);
    // ph3: quad(A1,B1); stage A0(t+2)->cur
    loadq(cur, 1, 1);
    stA(cur, 0, t+2);
    __builtin_amdgcn_sched_barrier(0);
    __builtin_amdgcn_s_barrier();
    asm volatile("s_waitcnt vmcnt(6) lgkmcnt(0)" ::: "memory");
    __builtin_amdgcn_sched_barrier(0);
    mmaq(1, 1);
    __builtin_amdgcn_s_barrier();
    __builtin_amdgcn_sched_barrier(0);
  }
  asm volatile("s_waitcnt vmcnt(0)" ::: "memory");  // drain clamped dummy stages

  #pragma unroll
  for (int jf = 0; jf < 4; ++jf){
    int col = n0 + (jf>>1)*128 + wc*32 + (jf&1)*16 + r15;
    float bb = bias ? bias[col] : 0.f;
    #pragma unroll
    for (int fi = 0; fi < 8; ++fi){
      #pragma unroll
      for (int jj = 0; jj < 4; ++jj){
        int row = m0 + (fi>>2)*128 + wr*64 + (fi&3)*16 + g*4 + jj;
        float v = acc[fi][jf][jj] + bb;
        if (act == 1) v = 0.5f * v * (1.f + erff(v * 0.70710678118654752f));
        C[(size_t)row*ldc + col] = f2bf(v);
      }
    }
  }
}

// ---------------- single-pass fused attention, online-softmax fold ----------------
// Block: 64 tokens x 128 cols (2 heads), 512 thr / 8 waves (wr 0..3 token 16-groups, h).
// Per K-step: stage x-tile + Wk-tile + Wv-tile (5 gl_lds), sync, 16 MFMA/wave (K and V),
// sync. At each modality end: scores via per-lane dot + shfl butterfly; fold
// ctx += e^s * (V+bv) unnormalized; divide by sum(e) at the end (exact, f32-safe).
// Raw scores to sbuf; k_wsm computes the head-averaged softmax weights.
__global__ __launch_bounds__(512, 4)
void k_attn1p(const u16* __restrict__ x0b, const u16* __restrict__ x1b, const u16* __restrict__ x2b,
              const u16* __restrict__ Wc0, const u16* __restrict__ Wc1, const u16* __restrict__ Wc2,
              const float* __restrict__ bc0, const float* __restrict__ bc1, const float* __restrict__ bc2,
              const u16* __restrict__ Qg, u16* __restrict__ ctx, float* __restrict__ sbuf)
{
  __shared__ __align__(16) u16 As[64*64];    // 8KB token tile
  __shared__ __align__(16) u16 Bk[128*64];   // 16KB K-weight tile
  __shared__ __align__(16) u16 Bv[128*64];   // 16KB V-weight tile

  const int tid = threadIdx.x, lane = tid & 63, wid = tid >> 6;
  const int wr = wid >> 1, h = wid & 1;
  const int r15 = lane & 15, g = lane >> 4;
  const int bid = blockIdx.x;
  const int xcd = bid & 7, bn = (bid >> 3) & 7, btb = (bid >> 6) * 8 + xcd;
  const int t0 = btb * 64, n0 = bn * 128;
  const int arow = tid >> 3, acol = (tid & 7) * 8;

  const u16* Xs[3] = { x0b, x1b, x2b };
  const u16* Ws[3] = { Wc0, Wc1, Wc2 };
  const float* Bc[3] = { bc0, bc1, bc2 };
  const int Ks[3] = { 256, 512, 1024 };

  f32x4 cx[4] = {};
  float dn[4] = {0.f, 0.f, 0.f, 0.f};

  #pragma unroll
  for (int m = 0; m < 3; ++m){
    const int K = Ks[m];
    const u16* X  = Xs[m];
    const u16* WK = Ws[m];
    const u16* WV = Ws[m] + (size_t)1024*K;
    f32x4 aK[4] = {}, aV[4] = {};
    for (int k0 = 0; k0 < K; k0 += 64){
      gl_lds16(X + (size_t)(t0+arow)*K + k0 + swz(arow, acol), &As[arow*64 + acol]);
      #pragma unroll
      for (int l = 0; l < 2; ++l){
        int row = l*64 + arow;
        gl_lds16(WK + (size_t)(n0+row)*K + k0 + swz(row, acol), &Bk[row*64 + acol]);
        gl_lds16(WV + (size_t)(n0+row)*K + k0 + swz(row, acol), &Bv[row*64 + acol]);
      }
      __syncthreads();
      #pragma unroll
      for (int k2 = 0; k2 < 2; ++k2){
        int ra = wr*16 + r15;
        bf16x8 a2 = *(const bf16x8*)&As[ra*64 + swz(ra, k2*32 + g*8)];
        #pragma unroll
        for (int j = 0; j < 4; ++j){
          int rb = h*64 + j*16 + r15;
          bf16x8 kb = *(const bf16x8*)&Bk[rb*64 + swz(rb, k2*32 + g*8)];
          bf16x8 vb = *(const bf16x8*)&Bv[rb*64 + swz(rb, k2*32 + g*8)];
          aK[j] = __builtin_amdgcn_mfma_f32_16x16x32_bf16(a2, kb, aK[j], 0, 0, 0);
          aV[j] = __builtin_amdgcn_mfma_f32_16x16x32_bf16(a2, vb, aV[j], 0, 0, 0);
        }
      }
      __syncthreads();
    }
    // modality fold
    float bkc[4], bvc[4];
    #pragma unroll
    for (int j = 0; j < 4; ++j){
      bkc[j] = Bc[m][n0 + h*64 + j*16 + r15];
      bvc[j] = Bc[m][1024 + n0 + h*64 + j*16 + r15];
    }
    #pragma unroll
    for (int jj = 0; jj < 4; ++jj){
      int tt = wr*16 + g*4 + jj;
      const u16* qrow = Qg + (size_t)(t0+tt)*1024 + n0 + h*64 + r15;
      float s = 0.f;
      #pragma unroll
      for (int j = 0; j < 4; ++j)
        s += (aK[j][jj] + bkc[j]) * bf2f(qrow[j*16]);
      s += __shfl_xor(s, 1); s += __shfl_xor(s, 2);
      s += __shfl_xor(s, 4); s += __shfl_xor(s, 8);
      s *= 0.125f;
      if (r15 == 0) sbuf[((size_t)(t0+tt)*16 + bn*2 + h)*3 + m] = s;
      float e = __expf(s);
      dn[jj] += e;
      #pragma unroll
      for (int j = 0; j < 4; ++j)
        cx[j][jj] += e * (aV[j][jj] + bvc[j]);
    }
  }
  #pragma unroll
  for (int jj = 0; jj < 4; ++jj){
    float inv = 1.f / dn[jj];
    int tt = wr*16 + g*4 + jj;
    #pragma unroll
    for (int j = 0; j < 4; ++j)
      ctx[(size_t)(t0+tt)*1024 + n0 + h*64 + j*16 + r15] = f2bf(cx[j][jj] * inv);
  }
}

// ---------------- LayerNorm (H=1024), optional bf16 residual, bf16 or f32 out ----------------
__global__ __launch_bounds__(256)
void k_ln(const u16* __restrict__ X, const u16* __restrict__ R,
          const float* __restrict__ gam, const float* __restrict__ bet,
          u16* __restrict__ outb, float* __restrict__ outf)
{
  __shared__ float rs[4], rq[4];
  const int t = blockIdx.x, tid = threadIdx.x;
  const size_t base = (size_t)t*1024 + tid*4;
  u16x4 xv = *(const u16x4*)&X[base];
  float v[4];
  #pragma unroll
  for (int i = 0; i < 4; ++i) v[i] = bf2f(xv[i]);
  if (R){
    u16x4 rv = *(const u16x4*)&R[base];
    #pragma unroll
    for (int i = 0; i < 4; ++i) v[i] += bf2f(rv[i]);
  }
  float s = v[0]+v[1]+v[2]+v[3];
  float q = v[0]*v[0]+v[1]*v[1]+v[2]*v[2]+v[3]*v[3];
  #pragma unroll
  for (int m = 1; m < 64; m <<= 1){ s += __shfl_xor(s, m); q += __shfl_xor(q, m); }
  if ((tid & 63) == 0){ rs[tid>>6] = s; rq[tid>>6] = q; }
  __syncthreads();
  s = rs[0]+rs[1]+rs[2]+rs[3];
  q = rq[0]+rq[1]+rq[2]+rq[3];
  float mean = s * (1.f/1024.f);
  float var  = q * (1.f/1024.f) - mean*mean;
  float rstd = rsqrtf(var + 1e-5f);
  int c0 = tid*4;
  if (outb){
    u16x4 o;
    #pragma unroll
    for (int i = 0; i < 4; ++i) o[i] = f2bf((v[i]-mean)*rstd*gam[c0+i] + bet[c0+i]);
    *(u16x4*)&outb[base] = o;
  } else {
    float4 o;
    o.x = (v[0]-mean)*rstd*gam[c0+0] + bet[c0+0];
    o.y = (v[1]-mean)*rstd*gam[c0+1] + bet[c0+1];
    o.z = (v[2]-mean)*rstd*gam[c0+2] + bet[c0+2];
    o.w = (v[3]-mean)*rstd*gam[c0+3] + bet[c0+3];
    *(float4*)&outf[base] = o;
  }
}

// ---------------- host launcher ----------------
extern "C" void kernel_launch(void* const* d_in, const int* in_sizes, int n_in,
                              void* d_out, int out_size, void* d_ws, size_t ws_size,
                              hipStream_t stream)
{
  (void)in_sizes; (void)n_in; (void)out_size;
  const float* x0  = (const float*)d_in[0];
  const float* x1  = (const float*)d_in[1];
  const float* x2  = (const float*)d_in[2];
  const float* sc  = (const float*)d_in[3];
  const float* Wp0 = (const float*)d_in[4];  const float* bp0 = (const float*)d_in[5];
  const float* Wp1 = (const float*)d_in[6];  const float* bp1 = (const float*)d_in[7];
  const float* Wq  = (const float*)d_in[8];  const float* bq  = (const float*)d_in[9];
  const float* Wk  = (const float*)d_in[10]; const float* bk  = (const float*)d_in[11];
  const float* Wv  = (const float*)d_in[12]; const float* bv  = (const float*)d_in[13];
  const float* Wo  = (const float*)d_in[14]; const float* bo  = (const float*)d_in[15];
  const float* qt  = (const float*)d_in[16];
  const float* g1  = (const float*)d_in[17]; const float* be1 = (const float*)d_in[18];
  const float* g2  = (const float*)d_in[19]; const float* be2 = (const float*)d_in[20];
  const float* W1  = (const float*)d_in[21]; const float* b1  = (const float*)d_in[22];
  const float* W2  = (const float*)d_in[23]; const float* b2  = (const float*)d_in[24];

  char* ws = (char*)d_ws;
  size_t off = 0;
  auto alloc = [&](size_t b)->char*{ char* p = ws + off; off += (b + 255) & ~(size_t)255; return p; };

  u16* Wqb   = (u16*)alloc((size_t)1024*1024*2);
  u16* Wob   = (u16*)alloc((size_t)1024*1024*2);
  u16* W1b   = (u16*)alloc((size_t)4096*1024*2);
  u16* W2b   = (u16*)alloc((size_t)1024*4096*2);
  u16* Wkvb  = (u16*)alloc((size_t)2048*1024*2);  // [Wk; Wv]
  u16* Wp0t  = (u16*)alloc((size_t)256*1024*2);   // Wp0^T
  u16* Wp1t  = (u16*)alloc((size_t)512*1024*2);   // Wp1^T
  u16* Wkv0c = (u16*)alloc((size_t)2048*256*2);   // [Wk;Wv]@Wp0
  u16* Wkv1c = (u16*)alloc((size_t)2048*512*2);   // [Wk;Wv]@Wp1
  float* bc0 = (float*)alloc((size_t)2048*4);
  float* bc1 = (float*)alloc((size_t)2048*4);
  float* bc2 = (float*)alloc((size_t)2048*4);
  char* regX  = alloc((size_t)BT*(256+512+1024)*2);  // x0b|x1b|x2b -> aob -> ff2b
  char* regQ1 = alloc((size_t)BT*1024*2);            // qb -> ctxb -> f1b
  char* regQ2 = alloc((size_t)BT*1024*2);            // Qb -> ff1c (fallback)
  float* sbuf = (float*)alloc((size_t)BT*48*4);      // raw per-head scores
  if (off > ws_size) return;
  u16* ff1big = nullptr;
  if (off + (size_t)16384*4096*2 <= ws_size) ff1big = (u16*)alloc((size_t)16384*4096*2);

  u16* x0b = (u16*)regX;
  u16* x1b = (u16*)(regX + (size_t)BT*256*2);
  u16* x2b = (u16*)(regX + (size_t)BT*768*2);
  u16* aob  = (u16*)regX;
  u16* ff2b = (u16*)regX;
  u16* qb   = (u16*)regQ1;
  u16* ctxb = (u16*)regQ1;
  u16* f1b  = (u16*)regQ1;
  u16* Qb   = (u16*)regQ2;

  dim3 B256(256), B512(512);
  auto cast4 = [&](const float* s, u16* d, int n, int grid){
    k_cast4<<<dim3(grid), B256, 0, stream>>>(s, d, n >> 2);
  };
  cast4(Wq, Wqb, 1024*1024, 1024);
  cast4(Wk, Wkvb, 1024*1024, 1024);
  cast4(Wv, Wkvb + (size_t)1024*1024, 1024*1024, 1024);
  cast4(Wo, Wob, 1024*1024, 1024);
  cast4(W1, W1b, 4096*1024, 1024);
  cast4(W2, W2b, 4096*1024, 1024);
  cast4(x0, x0b, BT*256, 1024);
  cast4(x1, x1b, BT*512, 1024);
  cast4(x2, x2b, BT*1024, 2048);
  k_transcast<<<dim3(8, 32),  B256, 0, stream>>>(Wp0, Wp0t, 1024, 256);
  k_transcast<<<dim3(16, 32), B256, 0, stream>>>(Wp1, Wp1t, 1024, 512);
  k_copyf<<<dim3(4), B256, 0, stream>>>(bk, bc2, 1024);
  k_copyf<<<dim3(4), B256, 0, stream>>>(bv, bc2 + 1024, 1024);
  k_matvec<<<dim3(512), B256, 0, stream>>>(Wkvb, bp0, bc2, bc0, 1024);
  k_matvec<<<dim3(512), B256, 0, stream>>>(Wkvb, bp1, bc2, bc1, 1024);
  k_qb<<<dim3(2048), B256, 0, stream>>>(qt, sc, qb, BT*256);

  // composite weights: Wkv @ Wp_m  (C[2048, IN_m])
  k_gemm<<<dim3(16, 2), B256, 0, stream>>>(Wkvb, 1024, Wp0t, 1024, 1024, nullptr, Wkv0c, 256, 0, 0);
  k_gemm<<<dim3(16, 4), B256, 0, stream>>>(Wkvb, 1024, Wp1t, 1024, 1024, nullptr, Wkv1c, 512, 0, 0);

  k_gemm<<<dim3(BT/128, 8), B256, 0, stream>>>(qb, 1024, Wqb, 1024, 1024, bq, Qb, 1024, 0, 0);
  k_attn1p<<<dim3(BT/64*8), B512, 0, stream>>>(x0b, x1b, x2b, Wkv0c, Wkv1c, Wkvb,
                                               bc0, bc1, bc2, Qb, ctxb, sbuf);
  k_gemm<<<dim3(BT/128, 8), B256, 0, stream>>>(ctxb, 1024, Wob, 1024, 1024, bo, aob, 1024, 0, 0);
  k_ln<<<dim3(BT), B256, 0, stream>>>(aob, nullptr, g1, be1, f1b, nullptr);

  if (ff1big){
    for (int c = 0; c < 2; ++c){
      const u16* fa = f1b + (size_t)c*16384*1024;
      k_gemm8x<<<dim3(1024), B512, 0, stream>>>(fa, 1024, W1b, 1024, 1024, b1, ff1big, 4096, 1, 16);
      k_gemm8x<<<dim3(256),  B512, 0, stream>>>(ff1big, 4096, W2b, 4096, 4096, b2,
                                                ff2b + (size_t)c*16384*1024, 1024, 0, 4);
    }
  } else {
    u16* ff1c = (u16*)regQ2;   // Qb dead after attn
    for (int c = 0; c < 4; ++c){
      const u16* fa = f1b + (size_t)c*8192*1024;
      k_gemm8x<<<dim3(512), B512, 0, stream>>>(fa, 1024, W1b, 1024, 1024, b1, ff1c, 4096, 1, 16);
      k_gemm8x<<<dim3(128), B512, 0, stream>>>(ff1c, 4096, W2b, 4096, 4096, b2,
                                               ff2b + (size_t)c*8192*1024, 1024, 0, 4);
    }
  }
  float* outf = (float*)d_out;
  k_ln<<<dim3(BT), B256, 0, stream>>>(ff2b, f1b, g2, be2, nullptr, outf);
  k_wsm<<<dim3(128), B256, 0, stream>>>(sbuf, outf + (size_t)BT*1024, BT);
}

// Round 11
// 1709.783 us; speedup vs baseline: 1.0057x; 1.0057x over previous
//
#include <hip/hip_runtime.h>
#include <hip/hip_bf16.h>
#include <math.h>

#define BT 32768        // B*T tokens
#define HH 1024

typedef unsigned short u16;
typedef __attribute__((ext_vector_type(4))) unsigned short u16x4;
typedef __attribute__((ext_vector_type(8))) unsigned short u16x8;
typedef __attribute__((ext_vector_type(8))) __bf16 bf16x8;
typedef __attribute__((ext_vector_type(4))) float f32x4;

#define DEVI static __device__ __forceinline__

DEVI u16 f2bf(float f){
  unsigned u = __builtin_bit_cast(unsigned, f);
  u += 0x7FFFu + ((u >> 16) & 1u);
  return (u16)(u >> 16);
}
DEVI float bf2f(u16 h){
  unsigned u = ((unsigned)h) << 16;
  return __builtin_bit_cast(float, u);
}
DEVI void gl_lds16(const void* g, void* l){
  __builtin_amdgcn_global_load_lds((const __attribute__((address_space(1))) void*)g,
                                   (__attribute__((address_space(3))) void*)l, 16, 0, 0);
}
// T2 swizzle: 16B-granule XOR within a 64-elem (128B) row. elem units of u16. Involution.
DEVI int swz(int row, int elem){ return elem ^ ((row & 7) << 3); }

// ---------------- elementwise prep kernels ----------------
__global__ void k_cast4(const float* __restrict__ s, u16* __restrict__ d, int n4){
  int i = blockIdx.x*blockDim.x + threadIdx.x;
  int st = gridDim.x*blockDim.x;
  for (; i < n4; i += st){
    float4 v = ((const float4*)s)[i];
    u16x4 o = { f2bf(v.x), f2bf(v.y), f2bf(v.z), f2bf(v.w) };
    ((u16x4*)d)[i] = o;
  }
}

// qb = bf16(query_token + static_context)
__global__ void k_qb(const float* __restrict__ qt, const float* __restrict__ sc,
                     u16* __restrict__ d, int n4){
  int i = blockIdx.x*blockDim.x + threadIdx.x;
  int st = gridDim.x*blockDim.x;
  for (; i < n4; i += st){
    int e = i*4; int c = e & 1023;
    float4 v = *(const float4*)&sc[e];
    float4 q = *(const float4*)&qt[c];
    u16x4 o = { f2bf(v.x+q.x), f2bf(v.y+q.y), f2bf(v.z+q.z), f2bf(v.w+q.w) };
    ((u16x4*)d)[i] = o;
  }
}

__global__ void k_copyf(const float* __restrict__ s, float* __restrict__ d, int n){
  int i = blockIdx.x*blockDim.x + threadIdx.x;
  int st = gridDim.x*blockDim.x;
  for (; i < n; i += st) d[i] = s[i];
}

// softmax per (t,h) over m=3: raw scores sbuf -> probs pbuf; head-mean -> wout
__global__ void k_psm(const float* __restrict__ s, float* __restrict__ p,
                      float* __restrict__ wout, int T){
  int t = blockIdx.x*blockDim.x + threadIdx.x;
  int st = gridDim.x*blockDim.x;
  for (; t < T; t += st){
    float a0 = 0.f, a1 = 0.f, a2 = 0.f;
    #pragma unroll
    for (int h = 0; h < 16; ++h){
      const float* b = s + (size_t)t*48 + h*3;
      float s0 = b[0], s1 = b[1], s2 = b[2];
      float mx = fmaxf(s0, fmaxf(s1, s2));
      float e0 = __expf(s0-mx), e1 = __expf(s1-mx), e2 = __expf(s2-mx);
      float inv = 1.f/(e0+e1+e2);
      e0 *= inv; e1 *= inv; e2 *= inv;
      float* q = p + (size_t)t*48 + h*3;
      q[0] = e0; q[1] = e1; q[2] = e2;
      a0 += e0; a1 += e1; a2 += e2;
    }
    wout[(size_t)t*3+0] = a0*0.0625f;
    wout[(size_t)t*3+1] = a1*0.0625f;
    wout[(size_t)t*3+2] = a2*0.0625f;
  }
}

// transpose-cast: s[R][C] f32 -> d[C][R] bf16
__global__ void k_transcast(const float* __restrict__ s, u16* __restrict__ d, int R, int C){
  __shared__ float tile[32][33];
  int c0 = blockIdx.x*32, r0 = blockIdx.y*32;
  int tx = threadIdx.x & 31, ty = threadIdx.x >> 5;   // 32 x 8
  #pragma unroll
  for (int i = 0; i < 32; i += 8) tile[ty+i][tx] = s[(size_t)(r0+ty+i)*C + c0+tx];
  __syncthreads();
  #pragma unroll
  for (int i = 0; i < 32; i += 8) d[(size_t)(c0+ty+i)*R + r0+tx] = f2bf(tile[tx][ty+i]);
}

// out[row] = dot(W[row,:](bf16), x(f32)) + badd[row], rows = gridDim.x*4
__global__ void k_matvec(const u16* __restrict__ W, const float* __restrict__ x,
                         const float* __restrict__ badd, float* __restrict__ out, int K){
  int row = blockIdx.x*4 + (threadIdx.x>>6);
  int lane = threadIdx.x & 63;
  float s = 0.f;
  for (int k = lane; k < K; k += 64) s += bf2f(W[(size_t)row*K + k]) * x[k];
  #pragma unroll
  for (int m = 1; m < 64; m <<= 1) s += __shfl_xor(s, m);
  if (lane == 0) out[row] = s + badd[row];
}

// ---------------- GEMM 128x128 (R2-proven) ----------------
__global__ __launch_bounds__(256, 3)
void k_gemm(const u16* __restrict__ A, int lda,
            const u16* __restrict__ B, int ldb, int K,
            const float* __restrict__ bias,
            u16* __restrict__ C, int ldc, int col0, int act)
{
  __shared__ u16 As[128*64];
  __shared__ u16 Bs[128*64];
  const int tid = threadIdx.x, lane = tid & 63, wid = tid >> 6;
  const int wr = wid >> 1, wc = wid & 1;
  const int r15 = lane & 15, g = lane >> 4;
  const int m0 = blockIdx.x * 128, n0 = blockIdx.y * 128;
  f32x4 acc[4][4] = {};

  for (int k0 = 0; k0 < K; k0 += 64){
    #pragma unroll
    for (int it = 0; it < 4; ++it){
      int c = it*256 + tid;
      int row = c >> 3;
      int ke = swz(row, (c & 7) * 8);
      gl_lds16(A + (size_t)(m0+row)*lda + (k0+ke), As + c*8);
      gl_lds16(B + (size_t)(n0+row)*ldb + (k0+ke), Bs + c*8);
    }
    __syncthreads();
    #pragma unroll
    for (int kk = 0; kk < 64; kk += 32){
      bf16x8 av[4], bvv[4];
      #pragma unroll
      for (int i = 0; i < 4; ++i){
        int row = wr*64 + i*16 + r15;
        av[i] = *(const bf16x8*)&As[row*64 + swz(row, kk + g*8)];
      }
      #pragma unroll
      for (int j = 0; j < 4; ++j){
        int row = wc*64 + j*16 + r15;
        bvv[j] = *(const bf16x8*)&Bs[row*64 + swz(row, kk + g*8)];
      }
      #pragma unroll
      for (int i = 0; i < 4; ++i)
        #pragma unroll
        for (int j = 0; j < 4; ++j)
          acc[i][j] = __builtin_amdgcn_mfma_f32_16x16x32_bf16(av[i], bvv[j], acc[i][j], 0, 0, 0);
    }
    __syncthreads();
  }
  #pragma unroll
  for (int j = 0; j < 4; ++j){
    int col = wc*64 + j*16 + r15;
    float bb = bias ? bias[n0 + col] : 0.f;
    #pragma unroll
    for (int i = 0; i < 4; ++i){
      #pragma unroll
      for (int jj = 0; jj < 4; ++jj){
        int row = wr*64 + i*16 + g*4 + jj;
        float v = acc[i][j][jj] + bb;
        if (act == 1) v = 0.5f * v * (1.f + erff(v * 0.70710678118654752f));
        C[(size_t)(m0+row)*ldc + col0 + n0 + col] = f2bf(v);
      }
    }
  }
}

// ---------------- attn pass 1: K-GEMM (k_gemm body) + score epilogue ----------------
// 128 tokens x 128 cols (2 heads), 256 thr, 4 waves at 64x64 (k_gemm density).
// Loops 3 modality K-panels; epilogue computes s[t,h] = (K[t]+bk).Q[t]/8 (wave covers
// exactly one head), writes raw scores. Acc reset is a SEPARATE loop after the full
// epilogue (R10 bug: inline reset destroyed acc[i][j=jj] needed by later jj).
__global__ __launch_bounds__(256, 3)
void k_attnp1(const u16* __restrict__ x0b, const u16* __restrict__ x1b, const u16* __restrict__ x2b,
              const u16* __restrict__ Wc0, const u16* __restrict__ Wc1, const u16* __restrict__ Wc2,
              const float* __restrict__ bc0, const float* __restrict__ bc1, const float* __restrict__ bc2,
              const u16* __restrict__ Qg, float* __restrict__ sbuf)
{
  __shared__ u16 As[128*64];
  __shared__ u16 Bs[128*64];
  const int tid = threadIdx.x, lane = tid & 63, wid = tid >> 6;
  const int wr = wid >> 1, wc = wid & 1;
  const int r15 = lane & 15, g = lane >> 4;
  const int bid = blockIdx.x;
  const int xcd = bid & 7, bn = (bid >> 3) & 7, btb = (bid >> 6) * 8 + xcd;
  const int t0 = btb * 128, n0 = bn * 128;

  const u16* Xs[3] = { x0b, x1b, x2b };
  const u16* Ws[3] = { Wc0, Wc1, Wc2 };
  const float* Bc[3] = { bc0, bc1, bc2 };
  const int Ks[3] = { 256, 512, 1024 };

  f32x4 acc[4][4] = {};

  #pragma unroll
  for (int m = 0; m < 3; ++m){
    const int K = Ks[m];
    const u16* X = Xs[m];
    const u16* W = Ws[m];
    for (int k0 = 0; k0 < K; k0 += 64){
      #pragma unroll
      for (int it = 0; it < 4; ++it){
        int c = it*256 + tid;
        int row = c >> 3;
        int ke = swz(row, (c & 7) * 8);
        gl_lds16(X + (size_t)(t0+row)*K + (k0+ke), As + c*8);
        gl_lds16(W + (size_t)(n0+row)*K + (k0+ke), Bs + c*8);
      }
      __syncthreads();
      #pragma unroll
      for (int kk = 0; kk < 64; kk += 32){
        bf16x8 av[4], bvv[4];
        #pragma unroll
        for (int i = 0; i < 4; ++i){
          int row = wr*64 + i*16 + r15;
          av[i] = *(const bf16x8*)&As[row*64 + swz(row, kk + g*8)];
        }
        #pragma unroll
        for (int j = 0; j < 4; ++j){
          int row = wc*64 + j*16 + r15;
          bvv[j] = *(const bf16x8*)&Bs[row*64 + swz(row, kk + g*8)];
        }
        #pragma unroll
        for (int i = 0; i < 4; ++i)
          #pragma unroll
          for (int j = 0; j < 4; ++j)
            acc[i][j] = __builtin_amdgcn_mfma_f32_16x16x32_bf16(av[i], bvv[j], acc[i][j], 0, 0, 0);
      }
      __syncthreads();
    }
    // score epilogue for modality m; this wave's head = bn*2 + wc
    float bkc[4];
    #pragma unroll
    for (int j = 0; j < 4; ++j) bkc[j] = Bc[m][n0 + wc*64 + j*16 + r15];
    #pragma unroll
    for (int i = 0; i < 4; ++i){
      #pragma unroll
      for (int jj = 0; jj < 4; ++jj){
        int row = wr*64 + i*16 + g*4 + jj;
        const u16* qrow = Qg + (size_t)(t0+row)*1024 + n0 + wc*64 + r15;
        float sv = 0.f;
        #pragma unroll
        for (int j = 0; j < 4; ++j)
          sv += (acc[i][j][jj] + bkc[j]) * bf2f(qrow[j*16]);
        sv += __shfl_xor(sv, 1); sv += __shfl_xor(sv, 2);
        sv += __shfl_xor(sv, 4); sv += __shfl_xor(sv, 8);
        if (r15 == 0) sbuf[((size_t)(t0+row)*16 + bn*2 + wc)*3 + m] = sv * 0.125f;
      }
    }
    // reset AFTER the full epilogue (all acc reads done)
    #pragma unroll
    for (int i = 0; i < 4; ++i)
      #pragma unroll
      for (int j = 0; j < 4; ++j)
        acc[i][j] = f32x4{0.f, 0.f, 0.f, 0.f};
  }
}

// ---------------- attn pass 2: ctx = sum_m (p_m . x_m) @ Wv_m^T + sum_m p_m bv_m ------
// Scaling x by p BEFORE the GEMM lets the modality loop accumulate into ONE acc[4][4].
// A staged per-head p-scaled (2 copies, reg-staged, swizzled-dest write); B via gl_lds.
__global__ __launch_bounds__(256, 3)
void k_attnp2(const u16* __restrict__ x0b, const u16* __restrict__ x1b, const u16* __restrict__ x2b,
              const u16* __restrict__ Wc0, const u16* __restrict__ Wc1, const u16* __restrict__ Wc2,
              const float* __restrict__ bc0, const float* __restrict__ bc1, const float* __restrict__ bc2,
              const float* __restrict__ pbuf, u16* __restrict__ ctx)
{
  __shared__ u16 As[2][128*64];    // per-head scaled token tile
  __shared__ u16 Bs[128*64];       // Wv panel tile
  __shared__ float pl[768];        // p[row][h][m]
  const int tid = threadIdx.x, lane = tid & 63, wid = tid >> 6;
  const int wr = wid >> 1, wc = wid & 1;
  const int r15 = lane & 15, g = lane >> 4;
  const int bid = blockIdx.x;
  const int xcd = bid & 7, bn = (bid >> 3) & 7, btb = (bid >> 6) * 8 + xcd;
  const int t0 = btb * 128, n0 = bn * 128;

  const u16* Xs[3] = { x0b, x1b, x2b };
  const u16* Ws[3] = { Wc0, Wc1, Wc2 };
  const float* Bc[3] = { bc0, bc1, bc2 };
  const int Ks[3] = { 256, 512, 1024 };

  // stage probs: pl[r*6 + h*3 + m]
  for (int idx = tid; idx < 768; idx += 256){
    int r = idx / 6, rem = idx - r*6;
    int h = rem / 3, m = rem - h*3;
    pl[idx] = pbuf[((size_t)(t0+r)*16 + bn*2 + h)*3 + m];
  }
  __syncthreads();

  const int hh = tid >> 7, rr = tid & 127;   // staging assignment: head, row
  f32x4 acc[4][4] = {};

  #pragma unroll
  for (int m = 0; m < 3; ++m){
    const int K = Ks[m];
    const u16* X = Xs[m];
    const u16* W = Ws[m] + (size_t)1024*K;   // V rows of composite weight
    const float psc = pl[rr*6 + hh*3 + m];
    for (int k0 = 0; k0 < K; k0 += 64){
      // A: p-scaled x, reg-staged, swizzled-dest write
      const u16* xrow = X + (size_t)(t0+rr)*K + k0;
      #pragma unroll
      for (int c0 = 0; c0 < 8; ++c0){
        u16x8 v = *(const u16x8*)(xrow + c0*8);
        u16x8 o;
        #pragma unroll
        for (int e = 0; e < 8; ++e) o[e] = f2bf(bf2f(v[e]) * psc);
        *(u16x8*)&As[hh][rr*64 + swz(rr, c0*8)] = o;
      }
      // B: gl_lds, pre-swizzled source / linear dest
      #pragma unroll
      for (int it = 0; it < 4; ++it){
        int c = it*256 + tid;
        int row = c >> 3;
        int ke = swz(row, (c & 7) * 8);
        gl_lds16(W + (size_t)(n0+row)*K + (k0+ke), Bs + c*8);
      }
      __syncthreads();
      #pragma unroll
      for (int kk = 0; kk < 64; kk += 32){
        bf16x8 av[4], bvv[4];
        #pragma unroll
        for (int i = 0; i < 4; ++i){
          int row = wr*64 + i*16 + r15;
          av[i] = *(const bf16x8*)&As[wc][row*64 + swz(row, kk + g*8)];
        }
        #pragma unroll
        for (int j = 0; j < 4; ++j){
          int row = wc*64 + j*16 + r15;
          bvv[j] = *(const bf16x8*)&Bs[row*64 + swz(row, kk + g*8)];
        }
        #pragma unroll
        for (int i = 0; i < 4; ++i)
          #pragma unroll
          for (int j = 0; j < 4; ++j)
            acc[i][j] = __builtin_amdgcn_mfma_f32_16x16x32_bf16(av[i], bvv[j], acc[i][j], 0, 0, 0);
      }
      __syncthreads();
    }
  }
  // epilogue: add p-weighted V-bias, write ctx
  float bvc[3][4];
  #pragma unroll
  for (int m = 0; m < 3; ++m)
    #pragma unroll
    for (int j = 0; j < 4; ++j)
      bvc[m][j] = Bc[m][1024 + n0 + wc*64 + j*16 + r15];
  #pragma unroll
  for (int i = 0; i < 4; ++i){
    #pragma unroll
    for (int jj = 0; jj < 4; ++jj){
      int row = wr*64 + i*16 + g*4 + jj;
      float p0 = pl[row*6 + wc*3 + 0];
      float p1 = pl[row*6 + wc*3 + 1];
      float p2 = pl[row*6 + wc*3 + 2];
      #pragma unroll
      for (int j = 0; j < 4; ++j){
        float v = acc[i][j][jj] + p0*bvc[0][j] + p1*bvc[1][j] + p2*bvc[2][j];
        ctx[(size_t)(t0+row)*1024 + n0 + wc*64 + j*16 + r15] = f2bf(v);
      }
    }
  }
}

// ---------------- LayerNorm (H=1024), optional bf16 residual, bf16 or f32 out ----------------
__global__ __launch_bounds__(256)
void k_ln(const u16* __restrict__ X, const u16* __restrict__ R,
          const float* __restrict__ gam, const float* __restrict__ bet,
          u16* __restrict__ outb, float* __restrict__ outf)
{
  __shared__ float rs[4], rq[4];
  const int t = blockIdx.x, tid = threadIdx.x;
  const size_t base = (size_t)t*1024 + tid*4;
  u16x4 xv = *(const u16x4*)&X[base];
  float v[4];
  #pragma unroll
  for (int i = 0; i < 4; ++i) v[i] = bf2f(xv[i]);
  if (R){
    u16x4 rv = *(const u16x4*)&R[base];
    #pragma unroll
    for (int i = 0; i < 4; ++i) v[i] += bf2f(rv[i]);
  }
  float s = v[0]+v[1]+v[2]+v[3];
  float q = v[0]*v[0]+v[1]*v[1]+v[2]*v[2]+v[3]*v[3];
  #pragma unroll
  for (int m = 1; m < 64; m <<= 1){ s += __shfl_xor(s, m); q += __shfl_xor(q, m); }
  if ((tid & 63) == 0){ rs[tid>>6] = s; rq[tid>>6] = q; }
  __syncthreads();
  s = rs[0]+rs[1]+rs[2]+rs[3];
  q = rq[0]+rq[1]+rq[2]+rq[3];
  float mean = s * (1.f/1024.f);
  float var  = q * (1.f/1024.f) - mean*mean;
  float rstd = rsqrtf(var + 1e-5f);
  int c0 = tid*4;
  if (outb){
    u16x4 o;
    #pragma unroll
    for (int i = 0; i < 4; ++i) o[i] = f2bf((v[i]-mean)*rstd*gam[c0+i] + bet[c0+i]);
    *(u16x4*)&outb[base] = o;
  } else {
    float4 o;
    o.x = (v[0]-mean)*rstd*gam[c0+0] + bet[c0+0];
    o.y = (v[1]-mean)*rstd*gam[c0+1] + bet[c0+1];
    o.z = (v[2]-mean)*rstd*gam[c0+2] + bet[c0+2];
    o.w = (v[3]-mean)*rstd*gam[c0+3] + bet[c0+3];
    *(float4*)&outf[base] = o;
  }
}

// ---------------- host launcher ----------------
extern "C" void kernel_launch(void* const* d_in, const int* in_sizes, int n_in,
                              void* d_out, int out_size, void* d_ws, size_t ws_size,
                              hipStream_t stream)
{
  (void)in_sizes; (void)n_in; (void)out_size;
  const float* x0  = (const float*)d_in[0];
  const float* x1  = (const float*)d_in[1];
  const float* x2  = (const float*)d_in[2];
  const float* sc  = (const float*)d_in[3];
  const float* Wp0 = (const float*)d_in[4];  const float* bp0 = (const float*)d_in[5];
  const float* Wp1 = (const float*)d_in[6];  const float* bp1 = (const float*)d_in[7];
  const float* Wq  = (const float*)d_in[8];  const float* bq  = (const float*)d_in[9];
  const float* Wk  = (const float*)d_in[10]; const float* bk  = (const float*)d_in[11];
  const float* Wv  = (const float*)d_in[12]; const float* bv  = (const float*)d_in[13];
  const float* Wo  = (const float*)d_in[14]; const float* bo  = (const float*)d_in[15];
  const float* qt  = (const float*)d_in[16];
  const float* g1  = (const float*)d_in[17]; const float* be1 = (const float*)d_in[18];
  const float* g2  = (const float*)d_in[19]; const float* be2 = (const float*)d_in[20];
  const float* W1  = (const float*)d_in[21]; const float* b1  = (const float*)d_in[22];
  const float* W2  = (const float*)d_in[23]; const float* b2  = (const float*)d_in[24];

  char* ws = (char*)d_ws;
  size_t off = 0;
  auto alloc = [&](size_t b)->char*{ char* p = ws + off; off += (b + 255) & ~(size_t)255; return p; };

  u16* Wqb   = (u16*)alloc((size_t)1024*1024*2);
  u16* Wob   = (u16*)alloc((size_t)1024*1024*2);
  u16* W1b   = (u16*)alloc((size_t)4096*1024*2);
  u16* W2b   = (u16*)alloc((size_t)1024*4096*2);
  u16* Wkvb  = (u16*)alloc((size_t)2048*1024*2);  // [Wk; Wv]
  u16* Wp0t  = (u16*)alloc((size_t)256*1024*2);   // Wp0^T
  u16* Wp1t  = (u16*)alloc((size_t)512*1024*2);   // Wp1^T
  u16* Wkv0c = (u16*)alloc((size_t)2048*256*2);   // [Wk;Wv]@Wp0
  u16* Wkv1c = (u16*)alloc((size_t)2048*512*2);   // [Wk;Wv]@Wp1
  float* bc0 = (float*)alloc((size_t)2048*4);
  float* bc1 = (float*)alloc((size_t)2048*4);
  float* bc2 = (float*)alloc((size_t)2048*4);
  char* regX  = alloc((size_t)BT*(256+512+1024)*2);  // x0b|x1b|x2b -> aob -> ff2b
  char* regQ1 = alloc((size_t)BT*1024*2);            // qb -> ctxb -> f1b
  char* regQ2 = alloc((size_t)BT*1024*2);            // Qb -> ff1c
  float* sbuf = (float*)alloc((size_t)BT*48*4);      // raw per-head scores
  float* pbuf = (float*)alloc((size_t)BT*48*4);      // per-head probs
  if (off > ws_size) return;

  u16* x0b = (u16*)regX;
  u16* x1b = (u16*)(regX + (size_t)BT*256*2);
  u16* x2b = (u16*)(regX + (size_t)BT*768*2);
  u16* aob  = (u16*)regX;
  u16* ff2b = (u16*)regX;
  u16* qb   = (u16*)regQ1;
  u16* ctxb = (u16*)regQ1;
  u16* f1b  = (u16*)regQ1;
  u16* Qb   = (u16*)regQ2;
  u16* ff1c = (u16*)regQ2;

  dim3 B256(256);
  auto cast4 = [&](const float* s, u16* d, int n, int grid){
    k_cast4<<<dim3(grid), B256, 0, stream>>>(s, d, n >> 2);
  };
  cast4(Wq, Wqb, 1024*1024, 1024);
  cast4(Wk, Wkvb, 1024*1024, 1024);
  cast4(Wv, Wkvb + (size_t)1024*1024, 1024*1024, 1024);
  cast4(Wo, Wob, 1024*1024, 1024);
  cast4(W1, W1b, 4096*1024, 1024);
  cast4(W2, W2b, 4096*1024, 1024);
  cast4(x0, x0b, BT*256, 1024);
  cast4(x1, x1b, BT*512, 1024);
  cast4(x2, x2b, BT*1024, 2048);
  k_transcast<<<dim3(8, 32),  B256, 0, stream>>>(Wp0, Wp0t, 1024, 256);
  k_transcast<<<dim3(16, 32), B256, 0, stream>>>(Wp1, Wp1t, 1024, 512);
  k_copyf<<<dim3(4), B256, 0, stream>>>(bk, bc2, 1024);
  k_copyf<<<dim3(4), B256, 0, stream>>>(bv, bc2 + 1024, 1024);
  k_matvec<<<dim3(512), B256, 0, stream>>>(Wkvb, bp0, bc2, bc0, 1024);
  k_matvec<<<dim3(512), B256, 0, stream>>>(Wkvb, bp1, bc2, bc1, 1024);
  k_qb<<<dim3(2048), B256, 0, stream>>>(qt, sc, qb, BT*256);

  // composite weights: Wkv @ Wp_m  (C[2048, IN_m])
  k_gemm<<<dim3(16, 2), B256, 0, stream>>>(Wkvb, 1024, Wp0t, 1024, 1024, nullptr, Wkv0c, 256, 0, 0);
  k_gemm<<<dim3(16, 4), B256, 0, stream>>>(Wkvb, 1024, Wp1t, 1024, 1024, nullptr, Wkv1c, 512, 0, 0);

  k_gemm<<<dim3(BT/128, 8), B256, 0, stream>>>(qb, 1024, Wqb, 1024, 1024, bq, Qb, 1024, 0, 0);
  k_attnp1<<<dim3(BT/128*8), B256, 0, stream>>>(x0b, x1b, x2b, Wkv0c, Wkv1c, Wkvb,
                                                bc0, bc1, bc2, Qb, sbuf);
  k_psm<<<dim3(128), B256, 0, stream>>>(sbuf, pbuf, (float*)d_out + (size_t)BT*1024, BT);
  k_attnp2<<<dim3(BT/128*8), B256, 0, stream>>>(x0b, x1b, x2b, Wkv0c, Wkv1c, Wkvb,
                                                bc0, bc1, bc2, pbuf, ctxb);
  k_gemm<<<dim3(BT/128, 8), B256, 0, stream>>>(ctxb, 1024, Wob, 1024, 1024, bo, aob, 1024, 0, 0);
  k_ln<<<dim3(BT), B256, 0, stream>>>(aob, nullptr, g1, be1, f1b, nullptr);

  for (int c = 0; c < 4; ++c){
    const u16* fa = f1b + (size_t)c*8192*1024;
    k_gemm<<<dim3(64, 32), B256, 0, stream>>>(fa, 1024, W1b, 1024, 1024, b1, ff1c, 4096, 0, 1);
    k_gemm<<<dim3(64, 8),  B256, 0, stream>>>(ff1c, 4096, W2b, 4096, 4096, b2,
                                              ff2b + (size_t)c*8192*1024, 1024, 0, 0);
  }
  float* outf = (float*)d_out;
  k_ln<<<dim3(BT), B256, 0, stream>>>(ff2b, f1b, g2, be2, nullptr, outf);
}

// Round 12
// 1581.941 us; speedup vs baseline: 1.0870x; 1.0808x over previous
//
#include <hip/hip_runtime.h>
#include <hip/hip_bf16.h>
#include <math.h>

#define BT 32768        // B*T tokens
#define HH 1024

typedef unsigned short u16;
typedef __attribute__((ext_vector_type(4))) unsigned short u16x4;
typedef __attribute__((ext_vector_type(8))) unsigned short u16x8;
typedef __attribute__((ext_vector_type(8))) __bf16 bf16x8;
typedef __attribute__((ext_vector_type(4))) float f32x4;

#define DEVI static __device__ __forceinline__

DEVI u16 f2bf(float f){
  unsigned u = __builtin_bit_cast(unsigned, f);
  u += 0x7FFFu + ((u >> 16) & 1u);
  return (u16)(u >> 16);
}
DEVI float bf2f(u16 h){
  unsigned u = ((unsigned)h) << 16;
  return __builtin_bit_cast(float, u);
}
DEVI void gl_lds16(const void* g, void* l){
  __builtin_amdgcn_global_load_lds((const __attribute__((address_space(1))) void*)g,
                                   (__attribute__((address_space(3))) void*)l, 16, 0, 0);
}
// T2 swizzle: 16B-granule XOR within a 64-elem (128B) row. elem units of u16. Involution.
DEVI int swz(int row, int elem){ return elem ^ ((row & 7) << 3); }

// ---------------- elementwise prep kernels ----------------
__global__ void k_cast4(const float* __restrict__ s, u16* __restrict__ d, int n4){
  int i = blockIdx.x*blockDim.x + threadIdx.x;
  int st = gridDim.x*blockDim.x;
  for (; i < n4; i += st){
    float4 v = ((const float4*)s)[i];
    u16x4 o = { f2bf(v.x), f2bf(v.y), f2bf(v.z), f2bf(v.w) };
    ((u16x4*)d)[i] = o;
  }
}

// qb = bf16(query_token + static_context)
__global__ void k_qb(const float* __restrict__ qt, const float* __restrict__ sc,
                     u16* __restrict__ d, int n4){
  int i = blockIdx.x*blockDim.x + threadIdx.x;
  int st = gridDim.x*blockDim.x;
  for (; i < n4; i += st){
    int e = i*4; int c = e & 1023;
    float4 v = *(const float4*)&sc[e];
    float4 q = *(const float4*)&qt[c];
    u16x4 o = { f2bf(v.x+q.x), f2bf(v.y+q.y), f2bf(v.z+q.z), f2bf(v.w+q.w) };
    ((u16x4*)d)[i] = o;
  }
}

__global__ void k_copyf(const float* __restrict__ s, float* __restrict__ d, int n){
  int i = blockIdx.x*blockDim.x + threadIdx.x;
  int st = gridDim.x*blockDim.x;
  for (; i < n; i += st) d[i] = s[i];
}

// softmax per (t,h) over m=3: raw scores sbuf -> probs pbuf; head-mean -> wout
__global__ void k_psm(const float* __restrict__ s, float* __restrict__ p,
                      float* __restrict__ wout, int T){
  int t = blockIdx.x*blockDim.x + threadIdx.x;
  int st = gridDim.x*blockDim.x;
  for (; t < T; t += st){
    float a0 = 0.f, a1 = 0.f, a2 = 0.f;
    #pragma unroll
    for (int h = 0; h < 16; ++h){
      const float* b = s + (size_t)t*48 + h*3;
      float s0 = b[0], s1 = b[1], s2 = b[2];
      float mx = fmaxf(s0, fmaxf(s1, s2));
      float e0 = __expf(s0-mx), e1 = __expf(s1-mx), e2 = __expf(s2-mx);
      float inv = 1.f/(e0+e1+e2);
      e0 *= inv; e1 *= inv; e2 *= inv;
      float* q = p + (size_t)t*48 + h*3;
      q[0] = e0; q[1] = e1; q[2] = e2;
      a0 += e0; a1 += e1; a2 += e2;
    }
    wout[(size_t)t*3+0] = a0*0.0625f;
    wout[(size_t)t*3+1] = a1*0.0625f;
    wout[(size_t)t*3+2] = a2*0.0625f;
  }
}

// transpose-cast: s[R][C] f32 -> d[C][R] bf16
__global__ void k_transcast(const float* __restrict__ s, u16* __restrict__ d, int R, int C){
  __shared__ float tile[32][33];
  int c0 = blockIdx.x*32, r0 = blockIdx.y*32;
  int tx = threadIdx.x & 31, ty = threadIdx.x >> 5;   // 32 x 8
  #pragma unroll
  for (int i = 0; i < 32; i += 8) tile[ty+i][tx] = s[(size_t)(r0+ty+i)*C + c0+tx];
  __syncthreads();
  #pragma unroll
  for (int i = 0; i < 32; i += 8) d[(size_t)(c0+ty+i)*R + r0+tx] = f2bf(tile[tx][ty+i]);
}

// out[row] = dot(W[row,:](bf16), x(f32)) + badd[row], rows = gridDim.x*4
__global__ void k_matvec(const u16* __restrict__ W, const float* __restrict__ x,
                         const float* __restrict__ badd, float* __restrict__ out, int K){
  int row = blockIdx.x*4 + (threadIdx.x>>6);
  int lane = threadIdx.x & 63;
  float s = 0.f;
  for (int k = lane; k < K; k += 64) s += bf2f(W[(size_t)row*K + k]) * x[k];
  #pragma unroll
  for (int m = 1; m < 64; m <<= 1) s += __shfl_xor(s, m);
  if (lane == 0) out[row] = s + badd[row];
}

// ---------------- GEMM 128x128 (R2-proven) ----------------
__global__ __launch_bounds__(256, 3)
void k_gemm(const u16* __restrict__ A, int lda,
            const u16* __restrict__ B, int ldb, int K,
            const float* __restrict__ bias,
            u16* __restrict__ C, int ldc, int col0, int act)
{
  __shared__ u16 As[128*64];
  __shared__ u16 Bs[128*64];
  const int tid = threadIdx.x, lane = tid & 63, wid = tid >> 6;
  const int wr = wid >> 1, wc = wid & 1;
  const int r15 = lane & 15, g = lane >> 4;
  const int m0 = blockIdx.x * 128, n0 = blockIdx.y * 128;
  f32x4 acc[4][4] = {};

  for (int k0 = 0; k0 < K; k0 += 64){
    #pragma unroll
    for (int it = 0; it < 4; ++it){
      int c = it*256 + tid;
      int row = c >> 3;
      int ke = swz(row, (c & 7) * 8);
      gl_lds16(A + (size_t)(m0+row)*lda + (k0+ke), As + c*8);
      gl_lds16(B + (size_t)(n0+row)*ldb + (k0+ke), Bs + c*8);
    }
    __syncthreads();
    #pragma unroll
    for (int kk = 0; kk < 64; kk += 32){
      bf16x8 av[4], bvv[4];
      #pragma unroll
      for (int i = 0; i < 4; ++i){
        int row = wr*64 + i*16 + r15;
        av[i] = *(const bf16x8*)&As[row*64 + swz(row, kk + g*8)];
      }
      #pragma unroll
      for (int j = 0; j < 4; ++j){
        int row = wc*64 + j*16 + r15;
        bvv[j] = *(const bf16x8*)&Bs[row*64 + swz(row, kk + g*8)];
      }
      #pragma unroll
      for (int i = 0; i < 4; ++i)
        #pragma unroll
        for (int j = 0; j < 4; ++j)
          acc[i][j] = __builtin_amdgcn_mfma_f32_16x16x32_bf16(av[i], bvv[j], acc[i][j], 0, 0, 0);
    }
    __syncthreads();
  }
  #pragma unroll
  for (int j = 0; j < 4; ++j){
    int col = wc*64 + j*16 + r15;
    float bb = bias ? bias[n0 + col] : 0.f;
    #pragma unroll
    for (int i = 0; i < 4; ++i){
      #pragma unroll
      for (int jj = 0; jj < 4; ++jj){
        int row = wr*64 + i*16 + g*4 + jj;
        float v = acc[i][j][jj] + bb;
        if (act == 1) v = 0.5f * v * (1.f + erff(v * 0.70710678118654752f));
        C[(size_t)(m0+row)*ldc + col0 + n0 + col] = f2bf(v);
      }
    }
  }
}

// ---------------- attn pass 1: K-GEMM (k_gemm body) + score epilogue ----------------
// 128 tokens x 128 cols (2 heads), 256 thr, 4 waves at 64x64 (k_gemm density).
// Loops 3 modality K-panels; epilogue computes s[t,h] = (K[t]+bk).Q[t]/8 (wave covers
// exactly one head), writes raw scores. Acc reset AFTER the full epilogue (R10 lesson).
__global__ __launch_bounds__(256, 3)
void k_attnp1(const u16* __restrict__ x0b, const u16* __restrict__ x1b, const u16* __restrict__ x2b,
              const u16* __restrict__ Wc0, const u16* __restrict__ Wc1, const u16* __restrict__ Wc2,
              const float* __restrict__ bc0, const float* __restrict__ bc1, const float* __restrict__ bc2,
              const u16* __restrict__ Qg, float* __restrict__ sbuf)
{
  __shared__ u16 As[128*64];
  __shared__ u16 Bs[128*64];
  const int tid = threadIdx.x, lane = tid & 63, wid = tid >> 6;
  const int wr = wid >> 1, wc = wid & 1;
  const int r15 = lane & 15, g = lane >> 4;
  const int bid = blockIdx.x;
  const int xcd = bid & 7, bn = (bid >> 3) & 7, btb = (bid >> 6) * 8 + xcd;
  const int t0 = btb * 128, n0 = bn * 128;

  const u16* Xs[3] = { x0b, x1b, x2b };
  const u16* Ws[3] = { Wc0, Wc1, Wc2 };
  const float* Bc[3] = { bc0, bc1, bc2 };
  const int Ks[3] = { 256, 512, 1024 };

  f32x4 acc[4][4] = {};

  #pragma unroll
  for (int m = 0; m < 3; ++m){
    const int K = Ks[m];
    const u16* X = Xs[m];
    const u16* W = Ws[m];
    for (int k0 = 0; k0 < K; k0 += 64){
      #pragma unroll
      for (int it = 0; it < 4; ++it){
        int c = it*256 + tid;
        int row = c >> 3;
        int ke = swz(row, (c & 7) * 8);
        gl_lds16(X + (size_t)(t0+row)*K + (k0+ke), As + c*8);
        gl_lds16(W + (size_t)(n0+row)*K + (k0+ke), Bs + c*8);
      }
      __syncthreads();
      #pragma unroll
      for (int kk = 0; kk < 64; kk += 32){
        bf16x8 av[4], bvv[4];
        #pragma unroll
        for (int i = 0; i < 4; ++i){
          int row = wr*64 + i*16 + r15;
          av[i] = *(const bf16x8*)&As[row*64 + swz(row, kk + g*8)];
        }
        #pragma unroll
        for (int j = 0; j < 4; ++j){
          int row = wc*64 + j*16 + r15;
          bvv[j] = *(const bf16x8*)&Bs[row*64 + swz(row, kk + g*8)];
        }
        #pragma unroll
        for (int i = 0; i < 4; ++i)
          #pragma unroll
          for (int j = 0; j < 4; ++j)
            acc[i][j] = __builtin_amdgcn_mfma_f32_16x16x32_bf16(av[i], bvv[j], acc[i][j], 0, 0, 0);
      }
      __syncthreads();
    }
    // score epilogue for modality m; this wave's head = bn*2 + wc
    float bkc[4];
    #pragma unroll
    for (int j = 0; j < 4; ++j) bkc[j] = Bc[m][n0 + wc*64 + j*16 + r15];
    #pragma unroll
    for (int i = 0; i < 4; ++i){
      #pragma unroll
      for (int jj = 0; jj < 4; ++jj){
        int row = wr*64 + i*16 + g*4 + jj;
        const u16* qrow = Qg + (size_t)(t0+row)*1024 + n0 + wc*64 + r15;
        float sv = 0.f;
        #pragma unroll
        for (int j = 0; j < 4; ++j)
          sv += (acc[i][j][jj] + bkc[j]) * bf2f(qrow[j*16]);
        sv += __shfl_xor(sv, 1); sv += __shfl_xor(sv, 2);
        sv += __shfl_xor(sv, 4); sv += __shfl_xor(sv, 8);
        if (r15 == 0) sbuf[((size_t)(t0+row)*16 + bn*2 + wc)*3 + m] = sv * 0.125f;
      }
    }
    // reset AFTER the full epilogue (all acc reads done)
    #pragma unroll
    for (int i = 0; i < 4; ++i)
      #pragma unroll
      for (int j = 0; j < 4; ++j)
        acc[i][j] = f32x4{0.f, 0.f, 0.f, 0.f};
  }
}

// ---------------- attn pass 2: ctx = sum_m p_m . (x_m @ Wv_m^T + bv_m) ----------------
// Exact k_gemm body (gl_lds both operands, 32 MFMA/step); per-modality acc, folded into
// cx with the per-row prob at each modality end (48 FMA/thread total -- VALU-trivial,
// fixes R11's in-loop p-scaling that made p2 VALU-bound at MfmaUtil 15%).
__global__ __launch_bounds__(256, 2)
void k_attnp2(const u16* __restrict__ x0b, const u16* __restrict__ x1b, const u16* __restrict__ x2b,
              const u16* __restrict__ Wc0, const u16* __restrict__ Wc1, const u16* __restrict__ Wc2,
              const float* __restrict__ bc0, const float* __restrict__ bc1, const float* __restrict__ bc2,
              const float* __restrict__ pbuf, u16* __restrict__ ctx)
{
  __shared__ u16 As[128*64];
  __shared__ u16 Bs[128*64];
  __shared__ float pl[768];        // p[row][h][m]
  const int tid = threadIdx.x, lane = tid & 63, wid = tid >> 6;
  const int wr = wid >> 1, wc = wid & 1;
  const int r15 = lane & 15, g = lane >> 4;
  const int bid = blockIdx.x;
  const int xcd = bid & 7, bn = (bid >> 3) & 7, btb = (bid >> 6) * 8 + xcd;
  const int t0 = btb * 128, n0 = bn * 128;

  const u16* Xs[3] = { x0b, x1b, x2b };
  const u16* Ws[3] = { Wc0, Wc1, Wc2 };
  const float* Bc[3] = { bc0, bc1, bc2 };
  const int Ks[3] = { 256, 512, 1024 };

  // stage probs: pl[r*6 + h*3 + m]
  for (int idx = tid; idx < 768; idx += 256){
    int r = idx / 6, rem = idx - r*6;
    int h = rem / 3, m = rem - h*3;
    pl[idx] = pbuf[((size_t)(t0+r)*16 + bn*2 + h)*3 + m];
  }
  __syncthreads();

  f32x4 cx[4][4] = {};

  #pragma unroll
  for (int m = 0; m < 3; ++m){
    const int K = Ks[m];
    const u16* X = Xs[m];
    const u16* W = Ws[m] + (size_t)1024*K;   // V rows of composite weight
    f32x4 acc[4][4] = {};
    for (int k0 = 0; k0 < K; k0 += 64){
      #pragma unroll
      for (int it = 0; it < 4; ++it){
        int c = it*256 + tid;
        int row = c >> 3;
        int ke = swz(row, (c & 7) * 8);
        gl_lds16(X + (size_t)(t0+row)*K + (k0+ke), As + c*8);
        gl_lds16(W + (size_t)(n0+row)*K + (k0+ke), Bs + c*8);
      }
      __syncthreads();
      #pragma unroll
      for (int kk = 0; kk < 64; kk += 32){
        bf16x8 av[4], bvv[4];
        #pragma unroll
        for (int i = 0; i < 4; ++i){
          int row = wr*64 + i*16 + r15;
          av[i] = *(const bf16x8*)&As[row*64 + swz(row, kk + g*8)];
        }
        #pragma unroll
        for (int j = 0; j < 4; ++j){
          int row = wc*64 + j*16 + r15;
          bvv[j] = *(const bf16x8*)&Bs[row*64 + swz(row, kk + g*8)];
        }
        #pragma unroll
        for (int i = 0; i < 4; ++i)
          #pragma unroll
          for (int j = 0; j < 4; ++j)
            acc[i][j] = __builtin_amdgcn_mfma_f32_16x16x32_bf16(av[i], bvv[j], acc[i][j], 0, 0, 0);
      }
      __syncthreads();
    }
    // fold: cx += p(row,m) * (acc + bv_m)
    float bvc[4];
    #pragma unroll
    for (int j = 0; j < 4; ++j) bvc[j] = Bc[m][1024 + n0 + wc*64 + j*16 + r15];
    #pragma unroll
    for (int i = 0; i < 4; ++i){
      #pragma unroll
      for (int jj = 0; jj < 4; ++jj){
        int row = wr*64 + i*16 + g*4 + jj;
        float p = pl[row*6 + wc*3 + m];
        #pragma unroll
        for (int j = 0; j < 4; ++j)
          cx[i][j][jj] += p * (acc[i][j][jj] + bvc[j]);
      }
    }
  }
  // write ctx
  #pragma unroll
  for (int i = 0; i < 4; ++i){
    #pragma unroll
    for (int jj = 0; jj < 4; ++jj){
      int row = wr*64 + i*16 + g*4 + jj;
      #pragma unroll
      for (int j = 0; j < 4; ++j)
        ctx[(size_t)(t0+row)*1024 + n0 + wc*64 + j*16 + r15] = f2bf(cx[i][j][jj]);
    }
  }
}

// ---------------- LayerNorm (H=1024), optional bf16 residual, bf16 or f32 out ----------------
__global__ __launch_bounds__(256)
void k_ln(const u16* __restrict__ X, const u16* __restrict__ R,
          const float* __restrict__ gam, const float* __restrict__ bet,
          u16* __restrict__ outb, float* __restrict__ outf)
{
  __shared__ float rs[4], rq[4];
  const int t = blockIdx.x, tid = threadIdx.x;
  const size_t base = (size_t)t*1024 + tid*4;
  u16x4 xv = *(const u16x4*)&X[base];
  float v[4];
  #pragma unroll
  for (int i = 0; i < 4; ++i) v[i] = bf2f(xv[i]);
  if (R){
    u16x4 rv = *(const u16x4*)&R[base];
    #pragma unroll
    for (int i = 0; i < 4; ++i) v[i] += bf2f(rv[i]);
  }
  float s = v[0]+v[1]+v[2]+v[3];
  float q = v[0]*v[0]+v[1]*v[1]+v[2]*v[2]+v[3]*v[3];
  #pragma unroll
  for (int m = 1; m < 64; m <<= 1){ s += __shfl_xor(s, m); q += __shfl_xor(q, m); }
  if ((tid & 63) == 0){ rs[tid>>6] = s; rq[tid>>6] = q; }
  __syncthreads();
  s = rs[0]+rs[1]+rs[2]+rs[3];
  q = rq[0]+rq[1]+rq[2]+rq[3];
  float mean = s * (1.f/1024.f);
  float var  = q * (1.f/1024.f) - mean*mean;
  float rstd = rsqrtf(var + 1e-5f);
  int c0 = tid*4;
  if (outb){
    u16x4 o;
    #pragma unroll
    for (int i = 0; i < 4; ++i) o[i] = f2bf((v[i]-mean)*rstd*gam[c0+i] + bet[c0+i]);
    *(u16x4*)&outb[base] = o;
  } else {
    float4 o;
    o.x = (v[0]-mean)*rstd*gam[c0+0] + bet[c0+0];
    o.y = (v[1]-mean)*rstd*gam[c0+1] + bet[c0+1];
    o.z = (v[2]-mean)*rstd*gam[c0+2] + bet[c0+2];
    o.w = (v[3]-mean)*rstd*gam[c0+3] + bet[c0+3];
    *(float4*)&outf[base] = o;
  }
}

// ---------------- host launcher ----------------
extern "C" void kernel_launch(void* const* d_in, const int* in_sizes, int n_in,
                              void* d_out, int out_size, void* d_ws, size_t ws_size,
                              hipStream_t stream)
{
  (void)in_sizes; (void)n_in; (void)out_size;
  const float* x0  = (const float*)d_in[0];
  const float* x1  = (const float*)d_in[1];
  const float* x2  = (const float*)d_in[2];
  const float* sc  = (const float*)d_in[3];
  const float* Wp0 = (const float*)d_in[4];  const float* bp0 = (const float*)d_in[5];
  const float* Wp1 = (const float*)d_in[6];  const float* bp1 = (const float*)d_in[7];
  const float* Wq  = (const float*)d_in[8];  const float* bq  = (const float*)d_in[9];
  const float* Wk  = (const float*)d_in[10]; const float* bk  = (const float*)d_in[11];
  const float* Wv  = (const float*)d_in[12]; const float* bv  = (const float*)d_in[13];
  const float* Wo  = (const float*)d_in[14]; const float* bo  = (const float*)d_in[15];
  const float* qt  = (const float*)d_in[16];
  const float* g1  = (const float*)d_in[17]; const float* be1 = (const float*)d_in[18];
  const float* g2  = (const float*)d_in[19]; const float* be2 = (const float*)d_in[20];
  const float* W1  = (const float*)d_in[21]; const float* b1  = (const float*)d_in[22];
  const float* W2  = (const float*)d_in[23]; const float* b2  = (const float*)d_in[24];

  char* ws = (char*)d_ws;
  size_t off = 0;
  auto alloc = [&](size_t b)->char*{ char* p = ws + off; off += (b + 255) & ~(size_t)255; return p; };

  u16* Wqb   = (u16*)alloc((size_t)1024*1024*2);
  u16* Wob   = (u16*)alloc((size_t)1024*1024*2);
  u16* W1b   = (u16*)alloc((size_t)4096*1024*2);
  u16* W2b   = (u16*)alloc((size_t)1024*4096*2);
  u16* Wkvb  = (u16*)alloc((size_t)2048*1024*2);  // [Wk; Wv]
  u16* Wp0t  = (u16*)alloc((size_t)256*1024*2);   // Wp0^T
  u16* Wp1t  = (u16*)alloc((size_t)512*1024*2);   // Wp1^T
  u16* Wkv0c = (u16*)alloc((size_t)2048*256*2);   // [Wk;Wv]@Wp0
  u16* Wkv1c = (u16*)alloc((size_t)2048*512*2);   // [Wk;Wv]@Wp1
  float* bc0 = (float*)alloc((size_t)2048*4);
  float* bc1 = (float*)alloc((size_t)2048*4);
  float* bc2 = (float*)alloc((size_t)2048*4);
  char* regX  = alloc((size_t)BT*(256+512+1024)*2);  // x0b|x1b|x2b -> aob -> ff2b
  char* regQ1 = alloc((size_t)BT*1024*2);            // qb -> ctxb -> f1b
  char* regQ2 = alloc((size_t)BT*1024*2);            // Qb -> ff1c
  float* sbuf = (float*)alloc((size_t)BT*48*4);      // raw per-head scores
  float* pbuf = (float*)alloc((size_t)BT*48*4);      // per-head probs
  if (off > ws_size) return;

  u16* x0b = (u16*)regX;
  u16* x1b = (u16*)(regX + (size_t)BT*256*2);
  u16* x2b = (u16*)(regX + (size_t)BT*768*2);
  u16* aob  = (u16*)regX;
  u16* ff2b = (u16*)regX;
  u16* qb   = (u16*)regQ1;
  u16* ctxb = (u16*)regQ1;
  u16* f1b  = (u16*)regQ1;
  u16* Qb   = (u16*)regQ2;
  u16* ff1c = (u16*)regQ2;

  dim3 B256(256);
  auto cast4 = [&](const float* s, u16* d, int n, int grid){
    k_cast4<<<dim3(grid), B256, 0, stream>>>(s, d, n >> 2);
  };
  cast4(Wq, Wqb, 1024*1024, 1024);
  cast4(Wk, Wkvb, 1024*1024, 1024);
  cast4(Wv, Wkvb + (size_t)1024*1024, 1024*1024, 1024);
  cast4(Wo, Wob, 1024*1024, 1024);
  cast4(W1, W1b, 4096*1024, 1024);
  cast4(W2, W2b, 4096*1024, 1024);
  cast4(x0, x0b, BT*256, 1024);
  cast4(x1, x1b, BT*512, 1024);
  cast4(x2, x2b, BT*1024, 2048);
  k_transcast<<<dim3(8, 32),  B256, 0, stream>>>(Wp0, Wp0t, 1024, 256);
  k_transcast<<<dim3(16, 32), B256, 0, stream>>>(Wp1, Wp1t, 1024, 512);
  k_copyf<<<dim3(4), B256, 0, stream>>>(bk, bc2, 1024);
  k_copyf<<<dim3(4), B256, 0, stream>>>(bv, bc2 + 1024, 1024);
  k_matvec<<<dim3(512), B256, 0, stream>>>(Wkvb, bp0, bc2, bc0, 1024);
  k_matvec<<<dim3(512), B256, 0, stream>>>(Wkvb, bp1, bc2, bc1, 1024);
  k_qb<<<dim3(2048), B256, 0, stream>>>(qt, sc, qb, BT*256);

  // composite weights: Wkv @ Wp_m  (C[2048, IN_m])
  k_gemm<<<dim3(16, 2), B256, 0, stream>>>(Wkvb, 1024, Wp0t, 1024, 1024, nullptr, Wkv0c, 256, 0, 0);
  k_gemm<<<dim3(16, 4), B256, 0, stream>>>(Wkvb, 1024, Wp1t, 1024, 1024, nullptr, Wkv1c, 512, 0, 0);

  k_gemm<<<dim3(BT/128, 8), B256, 0, stream>>>(qb, 1024, Wqb, 1024, 1024, bq, Qb, 1024, 0, 0);
  k_attnp1<<<dim3(BT/128*8), B256, 0, stream>>>(x0b, x1b, x2b, Wkv0c, Wkv1c, Wkvb,
                                                bc0, bc1, bc2, Qb, sbuf);
  k_psm<<<dim3(128), B256, 0, stream>>>(sbuf, pbuf, (float*)d_out + (size_t)BT*1024, BT);
  k_attnp2<<<dim3(BT/128*8), B256, 0, stream>>>(x0b, x1b, x2b, Wkv0c, Wkv1c, Wkvb,
                                                bc0, bc1, bc2, pbuf, ctxb);
  k_gemm<<<dim3(BT/128, 8), B256, 0, stream>>>(ctxb, 1024, Wob, 1024, 1024, bo, aob, 1024, 0, 0);
  k_ln<<<dim3(BT), B256, 0, stream>>>(aob, nullptr, g1, be1, f1b, nullptr);

  for (int c = 0; c < 4; ++c){
    const u16* fa = f1b + (size_t)c*8192*1024;
    k_gemm<<<dim3(64, 32), B256, 0, stream>>>(fa, 1024, W1b, 1024, 1024, b1, ff1c, 4096, 0, 1);
    k_gemm<<<dim3(64, 8),  B256, 0, stream>>>(ff1c, 4096, W2b, 4096, 4096, b2,
                                              ff2b + (size_t)c*8192*1024, 1024, 0, 0);
  }
  float* outf = (float*)d_out;
  k_ln<<<dim3(BT), B256, 0, stream>>>(ff2b, f1b, g2, be2, nullptr, outf);
}

// Round 13
// 1548.884 us; speedup vs baseline: 1.1102x; 1.0213x over previous
//
#include <hip/hip_runtime.h>
#include <hip/hip_bf16.h>
#include <math.h>

#define BT 32768        // B*T tokens
#define HH 1024

typedef unsigned short u16;
typedef __attribute__((ext_vector_type(4))) unsigned short u16x4;
typedef __attribute__((ext_vector_type(8))) unsigned short u16x8;
typedef __attribute__((ext_vector_type(8))) __bf16 bf16x8;
typedef __attribute__((ext_vector_type(4))) float f32x4;

#define DEVI static __device__ __forceinline__

DEVI u16 f2bf(float f){
  unsigned u = __builtin_bit_cast(unsigned, f);
  u += 0x7FFFu + ((u >> 16) & 1u);
  return (u16)(u >> 16);
}
DEVI float bf2f(u16 h){
  unsigned u = ((unsigned)h) << 16;
  return __builtin_bit_cast(float, u);
}
DEVI void gl_lds16(const void* g, void* l){
  __builtin_amdgcn_global_load_lds((const __attribute__((address_space(1))) void*)g,
                                   (__attribute__((address_space(3))) void*)l, 16, 0, 0);
}
// T2 swizzle: 16B-granule XOR within a 64-elem (128B) row. elem units of u16. Involution.
DEVI int swz(int row, int elem){ return elem ^ ((row & 7) << 3); }

// ---------------- elementwise prep kernels ----------------
__global__ void k_cast4(const float* __restrict__ s, u16* __restrict__ d, int n4){
  int i = blockIdx.x*blockDim.x + threadIdx.x;
  int st = gridDim.x*blockDim.x;
  for (; i < n4; i += st){
    float4 v = ((const float4*)s)[i];
    u16x4 o = { f2bf(v.x), f2bf(v.y), f2bf(v.z), f2bf(v.w) };
    ((u16x4*)d)[i] = o;
  }
}

// qb = bf16(query_token + static_context)
__global__ void k_qb(const float* __restrict__ qt, const float* __restrict__ sc,
                     u16* __restrict__ d, int n4){
  int i = blockIdx.x*blockDim.x + threadIdx.x;
  int st = gridDim.x*blockDim.x;
  for (; i < n4; i += st){
    int e = i*4; int c = e & 1023;
    float4 v = *(const float4*)&sc[e];
    float4 q = *(const float4*)&qt[c];
    u16x4 o = { f2bf(v.x+q.x), f2bf(v.y+q.y), f2bf(v.z+q.z), f2bf(v.w+q.w) };
    ((u16x4*)d)[i] = o;
  }
}

__global__ void k_copyf(const float* __restrict__ s, float* __restrict__ d, int n){
  int i = blockIdx.x*blockDim.x + threadIdx.x;
  int st = gridDim.x*blockDim.x;
  for (; i < n; i += st) d[i] = s[i];
}

// weights = mean over 16 heads of pbuf[t][h][m]
__global__ void k_wmean(const float* __restrict__ p, float* __restrict__ out, int n){
  int i = blockIdx.x*blockDim.x + threadIdx.x;
  int st = gridDim.x*blockDim.x;
  for (; i < n; i += st){
    int t = i/3, m = i - t*3;
    float s = 0.f;
    #pragma unroll
    for (int h = 0; h < 16; ++h) s += p[(size_t)t*48 + h*3 + m];
    out[i] = s * 0.0625f;
  }
}

// transpose-cast: s[R][C] f32 -> d[C][R] bf16
__global__ void k_transcast(const float* __restrict__ s, u16* __restrict__ d, int R, int C){
  __shared__ float tile[32][33];
  int c0 = blockIdx.x*32, r0 = blockIdx.y*32;
  int tx = threadIdx.x & 31, ty = threadIdx.x >> 5;   // 32 x 8
  #pragma unroll
  for (int i = 0; i < 32; i += 8) tile[ty+i][tx] = s[(size_t)(r0+ty+i)*C + c0+tx];
  __syncthreads();
  #pragma unroll
  for (int i = 0; i < 32; i += 8) d[(size_t)(c0+ty+i)*R + r0+tx] = f2bf(tile[tx][ty+i]);
}

// out[row] = dot(W[row,:](bf16), x(f32)) + badd[row], rows = gridDim.x*4
__global__ void k_matvec(const u16* __restrict__ W, const float* __restrict__ x,
                         const float* __restrict__ badd, float* __restrict__ out, int K){
  int row = blockIdx.x*4 + (threadIdx.x>>6);
  int lane = threadIdx.x & 63;
  float s = 0.f;
  for (int k = lane; k < K; k += 64) s += bf2f(W[(size_t)row*K + k]) * x[k];
  #pragma unroll
  for (int m = 1; m < 64; m <<= 1) s += __shfl_xor(s, m);
  if (lane == 0) out[row] = s + badd[row];
}

// ---------------- GEMM 128x128 (R2-proven) ----------------
__global__ __launch_bounds__(256, 3)
void k_gemm(const u16* __restrict__ A, int lda,
            const u16* __restrict__ B, int ldb, int K,
            const float* __restrict__ bias,
            u16* __restrict__ C, int ldc, int col0, int act)
{
  __shared__ u16 As[128*64];
  __shared__ u16 Bs[128*64];
  const int tid = threadIdx.x, lane = tid & 63, wid = tid >> 6;
  const int wr = wid >> 1, wc = wid & 1;
  const int r15 = lane & 15, g = lane >> 4;
  const int m0 = blockIdx.x * 128, n0 = blockIdx.y * 128;
  f32x4 acc[4][4] = {};

  for (int k0 = 0; k0 < K; k0 += 64){
    #pragma unroll
    for (int it = 0; it < 4; ++it){
      int c = it*256 + tid;
      int row = c >> 3;
      int ke = swz(row, (c & 7) * 8);
      gl_lds16(A + (size_t)(m0+row)*lda + (k0+ke), As + c*8);
      gl_lds16(B + (size_t)(n0+row)*ldb + (k0+ke), Bs + c*8);
    }
    __syncthreads();
    #pragma unroll
    for (int kk = 0; kk < 64; kk += 32){
      bf16x8 av[4], bvv[4];
      #pragma unroll
      for (int i = 0; i < 4; ++i){
        int row = wr*64 + i*16 + r15;
        av[i] = *(const bf16x8*)&As[row*64 + swz(row, kk + g*8)];
      }
      #pragma unroll
      for (int j = 0; j < 4; ++j){
        int row = wc*64 + j*16 + r15;
        bvv[j] = *(const bf16x8*)&Bs[row*64 + swz(row, kk + g*8)];
      }
      #pragma unroll
      for (int i = 0; i < 4; ++i)
        #pragma unroll
        for (int j = 0; j < 4; ++j)
          acc[i][j] = __builtin_amdgcn_mfma_f32_16x16x32_bf16(av[i], bvv[j], acc[i][j], 0, 0, 0);
    }
    __syncthreads();
  }
  #pragma unroll
  for (int j = 0; j < 4; ++j){
    int col = wc*64 + j*16 + r15;
    float bb = bias ? bias[n0 + col] : 0.f;
    #pragma unroll
    for (int i = 0; i < 4; ++i){
      #pragma unroll
      for (int jj = 0; jj < 4; ++jj){
        int row = wr*64 + i*16 + g*4 + jj;
        float v = acc[i][j][jj] + bb;
        if (act == 1) v = 0.5f * v * (1.f + erff(v * 0.70710678118654752f));
        C[(size_t)(m0+row)*ldc + col0 + n0 + col] = f2bf(v);
      }
    }
  }
}

// ---------------- fused attention: K-GEMM -> scores -> softmax -> V-GEMM -> ctx -------
// Block = 128 tokens x 128 cols (2 heads), 256 thr, 4 waves at 64x64 (k_gemm density).
// Q hoisted to registers ONCE (64 f32/thread, loads hide under first GEMM panel) and
// reused by all 3 modality score epilogues. Softmax is block-local (both heads in-block);
// probs stay in LDS for pass 2 and per-head probs go to pbuf for k_wmean. Pass 2 is
// R12's proven after-GEMM p-fold. XCD-contiguous bid remap keeps x panels L2-resident.
__global__ __launch_bounds__(256, 2)
void k_attnf(const u16* __restrict__ x0b, const u16* __restrict__ x1b, const u16* __restrict__ x2b,
             const u16* __restrict__ Wc0, const u16* __restrict__ Wc1, const u16* __restrict__ Wc2,
             const float* __restrict__ bc0, const float* __restrict__ bc1, const float* __restrict__ bc2,
             const u16* __restrict__ Qg, u16* __restrict__ ctx, float* __restrict__ pbuf)
{
  __shared__ u16 As[128*64];
  __shared__ u16 Bs[128*64];
  __shared__ float Sl[2*128*3];    // scores -> probs (in place)
  const int tid = threadIdx.x, lane = tid & 63, wid = tid >> 6;
  const int wr = wid >> 1, wc = wid & 1;
  const int r15 = lane & 15, g = lane >> 4;
  const int bid = blockIdx.x;
  const int xcd = bid & 7, bn = (bid >> 3) & 7, btb = (bid >> 6) * 8 + xcd;
  const int t0 = btb * 128, n0 = bn * 128;

  const u16* Xs[3] = { x0b, x1b, x2b };
  const u16* Ws[3] = { Wc0, Wc1, Wc2 };
  const float* Bc[3] = { bc0, bc1, bc2 };
  const int Ks[3] = { 256, 512, 1024 };

  // hoist Q fragments to registers (reused across all 3 modality epilogues)
  float qreg[4][4][4];
  #pragma unroll
  for (int i = 0; i < 4; ++i)
    #pragma unroll
    for (int jj = 0; jj < 4; ++jj){
      int row = wr*64 + i*16 + g*4 + jj;
      const u16* qr = Qg + (size_t)(t0+row)*1024 + n0 + wc*64 + r15;
      #pragma unroll
      for (int j = 0; j < 4; ++j) qreg[i][jj][j] = bf2f(qr[j*16]);
    }

  // ---------------- pass 1: K-GEMM panels + score epilogues ----------------
  #pragma unroll
  for (int m = 0; m < 3; ++m){
    const int K = Ks[m];
    const u16* X = Xs[m];
    const u16* W = Ws[m];
    f32x4 acc[4][4] = {};
    for (int k0 = 0; k0 < K; k0 += 64){
      #pragma unroll
      for (int it = 0; it < 4; ++it){
        int c = it*256 + tid;
        int row = c >> 3;
        int ke = swz(row, (c & 7) * 8);
        gl_lds16(X + (size_t)(t0+row)*K + (k0+ke), As + c*8);
        gl_lds16(W + (size_t)(n0+row)*K + (k0+ke), Bs + c*8);
      }
      __syncthreads();
      #pragma unroll
      for (int kk = 0; kk < 64; kk += 32){
        bf16x8 av[4], bvv[4];
        #pragma unroll
        for (int i = 0; i < 4; ++i){
          int row = wr*64 + i*16 + r15;
          av[i] = *(const bf16x8*)&As[row*64 + swz(row, kk + g*8)];
        }
        #pragma unroll
        for (int j = 0; j < 4; ++j){
          int row = wc*64 + j*16 + r15;
          bvv[j] = *(const bf16x8*)&Bs[row*64 + swz(row, kk + g*8)];
        }
        #pragma unroll
        for (int i = 0; i < 4; ++i)
          #pragma unroll
          for (int j = 0; j < 4; ++j)
            acc[i][j] = __builtin_amdgcn_mfma_f32_16x16x32_bf16(av[i], bvv[j], acc[i][j], 0, 0, 0);
      }
      __syncthreads();
    }
    // scores for modality m; this wave's head = bn*2 + wc
    float bkc[4];
    #pragma unroll
    for (int j = 0; j < 4; ++j) bkc[j] = Bc[m][n0 + wc*64 + j*16 + r15];
    #pragma unroll
    for (int i = 0; i < 4; ++i){
      #pragma unroll
      for (int jj = 0; jj < 4; ++jj){
        int row = wr*64 + i*16 + g*4 + jj;
        float sv = 0.f;
        #pragma unroll
        for (int j = 0; j < 4; ++j)
          sv += (acc[i][j][jj] + bkc[j]) * qreg[i][jj][j];
        sv += __shfl_xor(sv, 1); sv += __shfl_xor(sv, 2);
        sv += __shfl_xor(sv, 4); sv += __shfl_xor(sv, 8);
        if (r15 == 0) Sl[(wc*128 + row)*3 + m] = sv * 0.125f;
      }
    }
  }
  __syncthreads();

  // ---------------- softmax (block-local) + per-head prob store ----------------
  {
    int h2 = tid >> 7, tt = tid & 127;
    int base = (h2*128 + tt)*3;
    float s0 = Sl[base+0], s1 = Sl[base+1], s2 = Sl[base+2];
    float mx = fmaxf(s0, fmaxf(s1, s2));
    float e0 = __expf(s0-mx), e1 = __expf(s1-mx), e2 = __expf(s2-mx);
    float inv = 1.f/(e0+e1+e2);
    e0 *= inv; e1 *= inv; e2 *= inv;
    __syncthreads();                      // all reads of raw scores done
    Sl[base+0] = e0; Sl[base+1] = e1; Sl[base+2] = e2;
    float* pp = pbuf + ((size_t)(t0+tt)*16 + (bn*2 + h2))*3;
    pp[0] = e0; pp[1] = e1; pp[2] = e2;
  }
  __syncthreads();

  // ---------------- pass 2: V-GEMM panels + p-fold ----------------
  f32x4 cx[4][4] = {};
  #pragma unroll
  for (int m = 0; m < 3; ++m){
    const int K = Ks[m];
    const u16* X = Xs[m];
    const u16* W = Ws[m] + (size_t)1024*K;   // V rows of composite weight
    f32x4 acc[4][4] = {};
    for (int k0 = 0; k0 < K; k0 += 64){
      #pragma unroll
      for (int it = 0; it < 4; ++it){
        int c = it*256 + tid;
        int row = c >> 3;
        int ke = swz(row, (c & 7) * 8);
        gl_lds16(X + (size_t)(t0+row)*K + (k0+ke), As + c*8);
        gl_lds16(W + (size_t)(n0+row)*K + (k0+ke), Bs + c*8);
      }
      __syncthreads();
      #pragma unroll
      for (int kk = 0; kk < 64; kk += 32){
        bf16x8 av[4], bvv[4];
        #pragma unroll
        for (int i = 0; i < 4; ++i){
          int row = wr*64 + i*16 + r15;
          av[i] = *(const bf16x8*)&As[row*64 + swz(row, kk + g*8)];
        }
        #pragma unroll
        for (int j = 0; j < 4; ++j){
          int row = wc*64 + j*16 + r15;
          bvv[j] = *(const bf16x8*)&Bs[row*64 + swz(row, kk + g*8)];
        }
        #pragma unroll
        for (int i = 0; i < 4; ++i)
          #pragma unroll
          for (int j = 0; j < 4; ++j)
            acc[i][j] = __builtin_amdgcn_mfma_f32_16x16x32_bf16(av[i], bvv[j], acc[i][j], 0, 0, 0);
      }
      __syncthreads();
    }
    // fold: cx += p(row,m) * (acc + bv_m)
    float bvc[4];
    #pragma unroll
    for (int j = 0; j < 4; ++j) bvc[j] = Bc[m][1024 + n0 + wc*64 + j*16 + r15];
    #pragma unroll
    for (int i = 0; i < 4; ++i){
      #pragma unroll
      for (int jj = 0; jj < 4; ++jj){
        int row = wr*64 + i*16 + g*4 + jj;
        float p = Sl[(wc*128 + row)*3 + m];
        #pragma unroll
        for (int j = 0; j < 4; ++j)
          cx[i][j][jj] += p * (acc[i][j][jj] + bvc[j]);
      }
    }
  }
  // write ctx
  #pragma unroll
  for (int i = 0; i < 4; ++i){
    #pragma unroll
    for (int jj = 0; jj < 4; ++jj){
      int row = wr*64 + i*16 + g*4 + jj;
      #pragma unroll
      for (int j = 0; j < 4; ++j)
        ctx[(size_t)(t0+row)*1024 + n0 + wc*64 + j*16 + r15] = f2bf(cx[i][j][jj]);
    }
  }
}

// ---------------- LayerNorm (H=1024), optional bf16 residual, bf16 or f32 out ----------------
__global__ __launch_bounds__(256)
void k_ln(const u16* __restrict__ X, const u16* __restrict__ R,
          const float* __restrict__ gam, const float* __restrict__ bet,
          u16* __restrict__ outb, float* __restrict__ outf)
{
  __shared__ float rs[4], rq[4];
  const int t = blockIdx.x, tid = threadIdx.x;
  const size_t base = (size_t)t*1024 + tid*4;
  u16x4 xv = *(const u16x4*)&X[base];
  float v[4];
  #pragma unroll
  for (int i = 0; i < 4; ++i) v[i] = bf2f(xv[i]);
  if (R){
    u16x4 rv = *(const u16x4*)&R[base];
    #pragma unroll
    for (int i = 0; i < 4; ++i) v[i] += bf2f(rv[i]);
  }
  float s = v[0]+v[1]+v[2]+v[3];
  float q = v[0]*v[0]+v[1]*v[1]+v[2]*v[2]+v[3]*v[3];
  #pragma unroll
  for (int m = 1; m < 64; m <<= 1){ s += __shfl_xor(s, m); q += __shfl_xor(q, m); }
  if ((tid & 63) == 0){ rs[tid>>6] = s; rq[tid>>6] = q; }
  __syncthreads();
  s = rs[0]+rs[1]+rs[2]+rs[3];
  q = rq[0]+rq[1]+rq[2]+rq[3];
  float mean = s * (1.f/1024.f);
  float var  = q * (1.f/1024.f) - mean*mean;
  float rstd = rsqrtf(var + 1e-5f);
  int c0 = tid*4;
  if (outb){
    u16x4 o;
    #pragma unroll
    for (int i = 0; i < 4; ++i) o[i] = f2bf((v[i]-mean)*rstd*gam[c0+i] + bet[c0+i]);
    *(u16x4*)&outb[base] = o;
  } else {
    float4 o;
    o.x = (v[0]-mean)*rstd*gam[c0+0] + bet[c0+0];
    o.y = (v[1]-mean)*rstd*gam[c0+1] + bet[c0+1];
    o.z = (v[2]-mean)*rstd*gam[c0+2] + bet[c0+2];
    o.w = (v[3]-mean)*rstd*gam[c0+3] + bet[c0+3];
    *(float4*)&outf[base] = o;
  }
}

// ---------------- host launcher ----------------
extern "C" void kernel_launch(void* const* d_in, const int* in_sizes, int n_in,
                              void* d_out, int out_size, void* d_ws, size_t ws_size,
                              hipStream_t stream)
{
  (void)in_sizes; (void)n_in; (void)out_size;
  const float* x0  = (const float*)d_in[0];
  const float* x1  = (const float*)d_in[1];
  const float* x2  = (const float*)d_in[2];
  const float* sc  = (const float*)d_in[3];
  const float* Wp0 = (const float*)d_in[4];  const float* bp0 = (const float*)d_in[5];
  const float* Wp1 = (const float*)d_in[6];  const float* bp1 = (const float*)d_in[7];
  const float* Wq  = (const float*)d_in[8];  const float* bq  = (const float*)d_in[9];
  const float* Wk  = (const float*)d_in[10]; const float* bk  = (const float*)d_in[11];
  const float* Wv  = (const float*)d_in[12]; const float* bv  = (const float*)d_in[13];
  const float* Wo  = (const float*)d_in[14]; const float* bo  = (const float*)d_in[15];
  const float* qt  = (const float*)d_in[16];
  const float* g1  = (const float*)d_in[17]; const float* be1 = (const float*)d_in[18];
  const float* g2  = (const float*)d_in[19]; const float* be2 = (const float*)d_in[20];
  const float* W1  = (const float*)d_in[21]; const float* b1  = (const float*)d_in[22];
  const float* W2  = (const float*)d_in[23]; const float* b2  = (const float*)d_in[24];

  char* ws = (char*)d_ws;
  size_t off = 0;
  auto alloc = [&](size_t b)->char*{ char* p = ws + off; off += (b + 255) & ~(size_t)255; return p; };

  u16* Wqb   = (u16*)alloc((size_t)1024*1024*2);
  u16* Wob   = (u16*)alloc((size_t)1024*1024*2);
  u16* W1b   = (u16*)alloc((size_t)4096*1024*2);
  u16* W2b   = (u16*)alloc((size_t)1024*4096*2);
  u16* Wkvb  = (u16*)alloc((size_t)2048*1024*2);  // [Wk; Wv]
  u16* Wp0t  = (u16*)alloc((size_t)256*1024*2);   // Wp0^T
  u16* Wp1t  = (u16*)alloc((size_t)512*1024*2);   // Wp1^T
  u16* Wkv0c = (u16*)alloc((size_t)2048*256*2);   // [Wk;Wv]@Wp0
  u16* Wkv1c = (u16*)alloc((size_t)2048*512*2);   // [Wk;Wv]@Wp1
  float* bc0 = (float*)alloc((size_t)2048*4);
  float* bc1 = (float*)alloc((size_t)2048*4);
  float* bc2 = (float*)alloc((size_t)2048*4);
  char* regX  = alloc((size_t)BT*(256+512+1024)*2);  // x0b|x1b|x2b -> aob -> ff2b
  char* regQ1 = alloc((size_t)BT*1024*2);            // qb -> ctxb -> f1b
  char* regQ2 = alloc((size_t)BT*1024*2);            // Qb -> ff1c
  float* pbuf = (float*)alloc((size_t)BT*48*4);      // per-head probs
  if (off > ws_size) return;

  u16* x0b = (u16*)regX;
  u16* x1b = (u16*)(regX + (size_t)BT*256*2);
  u16* x2b = (u16*)(regX + (size_t)BT*768*2);
  u16* aob  = (u16*)regX;
  u16* ff2b = (u16*)regX;
  u16* qb   = (u16*)regQ1;
  u16* ctxb = (u16*)regQ1;
  u16* f1b  = (u16*)regQ1;
  u16* Qb   = (u16*)regQ2;
  u16* ff1c = (u16*)regQ2;

  dim3 B256(256);
  auto cast4 = [&](const float* s, u16* d, int n, int grid){
    k_cast4<<<dim3(grid), B256, 0, stream>>>(s, d, n >> 2);
  };
  cast4(Wq, Wqb, 1024*1024, 1024);
  cast4(Wk, Wkvb, 1024*1024, 1024);
  cast4(Wv, Wkvb + (size_t)1024*1024, 1024*1024, 1024);
  cast4(Wo, Wob, 1024*1024, 1024);
  cast4(W1, W1b, 4096*1024, 1024);
  cast4(W2, W2b, 4096*1024, 1024);
  cast4(x0, x0b, BT*256, 1024);
  cast4(x1, x1b, BT*512, 1024);
  cast4(x2, x2b, BT*1024, 2048);
  k_transcast<<<dim3(8, 32),  B256, 0, stream>>>(Wp0, Wp0t, 1024, 256);
  k_transcast<<<dim3(16, 32), B256, 0, stream>>>(Wp1, Wp1t, 1024, 512);
  k_copyf<<<dim3(4), B256, 0, stream>>>(bk, bc2, 1024);
  k_copyf<<<dim3(4), B256, 0, stream>>>(bv, bc2 + 1024, 1024);
  k_matvec<<<dim3(512), B256, 0, stream>>>(Wkvb, bp0, bc2, bc0, 1024);
  k_matvec<<<dim3(512), B256, 0, stream>>>(Wkvb, bp1, bc2, bc1, 1024);
  k_qb<<<dim3(2048), B256, 0, stream>>>(qt, sc, qb, BT*256);

  // composite weights: Wkv @ Wp_m  (C[2048, IN_m])
  k_gemm<<<dim3(16, 2), B256, 0, stream>>>(Wkvb, 1024, Wp0t, 1024, 1024, nullptr, Wkv0c, 256, 0, 0);
  k_gemm<<<dim3(16, 4), B256, 0, stream>>>(Wkvb, 1024, Wp1t, 1024, 1024, nullptr, Wkv1c, 512, 0, 0);

  k_gemm<<<dim3(BT/128, 8), B256, 0, stream>>>(qb, 1024, Wqb, 1024, 1024, bq, Qb, 1024, 0, 0);
  k_attnf<<<dim3(BT/128*8), B256, 0, stream>>>(x0b, x1b, x2b, Wkv0c, Wkv1c, Wkvb,
                                               bc0, bc1, bc2, Qb, ctxb, pbuf);
  float* outf = (float*)d_out;
  k_wmean<<<dim3(384), B256, 0, stream>>>(pbuf, outf + (size_t)BT*1024, BT*3);
  k_gemm<<<dim3(BT/128, 8), B256, 0, stream>>>(ctxb, 1024, Wob, 1024, 1024, bo, aob, 1024, 0, 0);
  k_ln<<<dim3(BT), B256, 0, stream>>>(aob, nullptr, g1, be1, f1b, nullptr);

  for (int c = 0; c < 4; ++c){
    const u16* fa = f1b + (size_t)c*8192*1024;
    k_gemm<<<dim3(64, 32), B256, 0, stream>>>(fa, 1024, W1b, 1024, 1024, b1, ff1c, 4096, 0, 1);
    k_gemm<<<dim3(64, 8),  B256, 0, stream>>>(ff1c, 4096, W2b, 4096, 4096, b2,
                                              ff2b + (size_t)c*8192*1024, 1024, 0, 0);
  }
  k_ln<<<dim3(BT), B256, 0, stream>>>(ff2b, f1b, g2, be2, nullptr, outf);
}